// Round 4
// baseline (402.449 us; speedup 1.0000x reference)
//
#include <hip/hip_runtime.h>
#include <hip/hip_bf16.h>
#include <math.h>

// ---------------- problem constants ----------------
#define BATCH   1024
#define NUMPT   100
#define NVAR    11
#define NOBS    10
#define HID     1024
#define INPD    55
#define TRAJD   200
#define ENCIN   (INPD + TRAJD)   // 255
#define DECIN   (2 + INPD)       // 57

#define T_FIN_C   15.0f
#define K_P_C     20.0f
#define K_D_C     8.944271909999159f   // 2*sqrt(20)
#define K_P_V_C   20.0f
#define A_OBS_C   8.0f
#define B_OBS_C   4.2f
#define RHO_V_C      1.0f
#define RHO_PROJ_C   1.0f
#define RHO_LANE_C   100.0f
#define RHO_OBS_C    100.0f
#define RHO_OFFSET_C 1.0f
#define RHO_INEQ_C   100.0f
#define V_MIN_C   0.1f
#define V_MAX_C   30.0f
#define A_MAX_C   8.0f
#define MAXIT     20

// workspace layout (float offsets)
#define WS_INV1X  0      // 14x14
#define WS_INV1Y  256    // 15x15
#define WS_INV2X  512    // 14x14
#define WS_INV2Y  768    // 15x15
#define WS_SVD    1024   // 4x11 chunk-summed A_vd
#define WS_SPD    1088   // 4x11 chunk-summed A_pd
#define WS_QX     1152   // 11x11  Qx = cost2_x - I
#define WS_QY     1280   // 11x11  Qy = cost2_y - I
#define WS_BIG    2048

// ---------------------------------------------------------------------------
// Precompute: KKT matrices + inverses (GJ w/ partial pivoting), Qx/Qy,
// chunk-summed A_vd/A_pd. grid = 4 blocks, 256 threads.
// ---------------------------------------------------------------------------
__global__ __launch_bounds__(256) void precompute_kernel(
    const float* __restrict__ Pg, const float* __restrict__ Pdg,
    const float* __restrict__ Pddg, float* __restrict__ ws)
{
    __shared__ float sP[NUMPT*NVAR], sPd[NUMPT*NVAR], sPdd[NUMPT*NVAR];
    __shared__ float aug[15][31];
    __shared__ float fcol[15];
    __shared__ float s_pivinv;
    __shared__ int   s_pidx;
    const int tid = threadIdx.x, bid = blockIdx.x;

    for (int i = tid; i < NUMPT*NVAR; i += blockDim.x) {
        sP[i] = Pg[i]; sPd[i] = Pdg[i]; sPdd[i] = Pddg[i];
    }
    for (int i = tid; i < 15*31; i += blockDim.x) (&aug[0][0])[i] = 0.0f;
    __syncthreads();

    const int N = (bid == 0 || bid == 2) ? 14 : 15;

    if (tid < 121) {
        const int i = tid / 11, j = tid % 11;
        float s = 0.0f;
        if (bid == 0) {
            for (int t = 0; t < NUMPT; ++t) {
                float pdd_i = sPdd[t*NVAR+i], pdd_j = sPdd[t*NVAR+j];
                float av_i = pdd_i - K_P_V_C * sPd[t*NVAR+i];
                float av_j = pdd_j - K_P_V_C * sPd[t*NVAR+j];
                s += pdd_i*pdd_j + RHO_V_C * av_i*av_j;
            }
        } else if (bid == 1) {
            for (int t = 0; t < NUMPT; ++t) {
                float pdd_i = sPdd[t*NVAR+i], pdd_j = sPdd[t*NVAR+j];
                float ap_i = pdd_i - K_P_C*sP[t*NVAR+i] - K_D_C*sPd[t*NVAR+i];
                float ap_j = pdd_j - K_P_C*sP[t*NVAR+j] - K_D_C*sPd[t*NVAR+j];
                s += pdd_i*pdd_j + RHO_OFFSET_C * ap_i*ap_j;
            }
        } else {
            float obs_w = RHO_OBS_C * (float)NOBS;
            if (bid == 3) obs_w += RHO_LANE_C * 2.0f;
            for (int t = 0; t < NUMPT; ++t) {
                float p_i = sP[t*NVAR+i],   p_j = sP[t*NVAR+j];
                float pd_i = sPd[t*NVAR+i], pd_j = sPd[t*NVAR+j];
                float pdd_i = sPdd[t*NVAR+i], pdd_j = sPdd[t*NVAR+j];
                s += obs_w*p_i*p_j + RHO_INEQ_C*(pdd_i*pdd_j + pd_i*pd_j);
            }
            if (i == j) s += RHO_PROJ_C;
        }
        aug[i][j] = s;
    }
    if (tid < 11) {
        const int i = tid;
        float a0 = sP[i], a1 = sPd[i], a2 = sPdd[i];
        aug[i][11] = a0; aug[11][i] = a0;
        aug[i][12] = a1; aug[12][i] = a1;
        aug[i][13] = a2; aug[13][i] = a2;
        if (N == 15) { float a3 = sPd[99*NVAR + i]; aug[i][14] = a3; aug[14][i] = a3; }
    }
    if (tid < N) aug[tid][N + tid] = 1.0f;

    if (bid == 0 && tid < 44) {
        const int c = tid / 11, k = tid % 11;
        float sv = 0.0f, sp = 0.0f;
        for (int t = 25*c; t < 25*c + 25; ++t) {
            float p = sP[t*NVAR+k], pd = sPd[t*NVAR+k], pdd = sPdd[t*NVAR+k];
            sv += pdd - K_P_V_C * pd;
            sp += pdd - K_P_C * p - K_D_C * pd;
        }
        ws[WS_SVD + tid] = sv;
        ws[WS_SPD + tid] = sp;
    }
    __syncthreads();

    if ((bid == 2 || bid == 3) && tid < 121) {
        float v = aug[tid/11][tid%11];
        if (tid/11 == tid%11) v -= RHO_PROJ_C;
        ws[(bid == 2 ? WS_QX : WS_QY) + tid] = v;
    }

    for (int k = 0; k < N; ++k) {
        if (tid == 0) {
            int p = k; float best = fabsf(aug[k][k]);
            for (int i = k+1; i < N; ++i) {
                float v = fabsf(aug[i][k]);
                if (v > best) { best = v; p = i; }
            }
            s_pidx = p;
        }
        __syncthreads();
        const int p = s_pidx;
        if (p != k && tid < 2*N) {
            float tmp = aug[k][tid]; aug[k][tid] = aug[p][tid]; aug[p][tid] = tmp;
        }
        __syncthreads();
        if (tid == 0) s_pivinv = 1.0f / aug[k][k];
        __syncthreads();
        if (tid < 2*N) aug[k][tid] *= s_pivinv;
        __syncthreads();
        if (tid < N) fcol[tid] = (tid == k) ? 0.0f : aug[tid][k];
        __syncthreads();
        for (int idx = tid; idx < N*2*N; idx += blockDim.x) {
            const int i = idx / (2*N), j = idx % (2*N);
            if (i != k) aug[i][j] = fmaf(-fcol[i], aug[k][j], aug[i][j]);
        }
        __syncthreads();
    }

    float* dst = ws + (bid == 0 ? WS_INV1X : bid == 1 ? WS_INV1Y
                      : bid == 2 ? WS_INV2X : WS_INV2Y);
    for (int idx = tid; idx < N*N; idx += blockDim.x)
        dst[idx] = aug[idx / N][N + idx % N];
}

// ---------------------------------------------------------------------------
__global__ __launch_bounds__(256) void prep_kernel(
    const float* __restrict__ inp, const float* __restrict__ traj,
    const float* __restrict__ mean, const float* __restrict__ stdv,
    float* __restrict__ enc_in, float* __restrict__ dec_in)
{
    const int b = blockIdx.x, t = threadIdx.x;
    if (t < INPD) {
        float v = (inp[b*INPD + t] - mean[t]) / stdv[t];
        enc_in[b*ENCIN + t] = v;
        dec_in[b*DECIN + 2 + t] = v;
    } else if (t < ENCIN) {
        enc_in[b*ENCIN + t] = traj[b*TRAJD + (t - INPD)];
    }
}

// ---------------------------------------------------------------------------
// Split-K tiled fp32 GEMM. 64x64 tile, BK=16, 256 threads, 4x4 micro-tile.
// ---------------------------------------------------------------------------
__global__ __launch_bounds__(256) void gemm_splitk(
    const float* __restrict__ A, const float* __restrict__ W,
    float* __restrict__ pbuf, int M, int N, int K, int chunk)
{
    __shared__ float As[16][68];   // [k][row]
    __shared__ float Bs[16][68];   // [k][col]
    const int tid = threadIdx.x;
    const int tx = tid & 15, ty = tid >> 4;
    const int row0 = blockIdx.y * 64, col0 = blockIdx.x * 64;
    const int s = blockIdx.z;
    const int kS = s * chunk;
    const int kE = min(K, kS + chunk);
    float* C = pbuf + (size_t)s * M * N;
    float acc[4][4] = {};

    for (int k0 = kS; k0 < kE; k0 += 16) {
        {
            const int c = tid & 15, r = tid >> 4;
            const int kk = k0 + c;
            #pragma unroll
            for (int p = 0; p < 4; ++p) {
                const int rr = r + 16*p;
                As[c][rr] = (kk < kE) ? A[(size_t)(row0 + rr)*K + kk] : 0.0f;
            }
        }
        {
            const int n = tid & 63, c2 = tid >> 6;
            #pragma unroll
            for (int p = 0; p < 4; ++p) {
                const int kk = k0 + c2 + 4*p;
                Bs[c2 + 4*p][n] = (kk < kE) ? W[(size_t)kk*N + col0 + n] : 0.0f;
            }
        }
        __syncthreads();
        #pragma unroll
        for (int kk = 0; kk < 16; ++kk) {
            float4 a4 = *(const float4*)&As[kk][ty*4];
            float4 b4 = *(const float4*)&Bs[kk][tx*4];
            float a[4] = {a4.x, a4.y, a4.z, a4.w};
            float bb[4] = {b4.x, b4.y, b4.z, b4.w};
            #pragma unroll
            for (int i = 0; i < 4; ++i)
                #pragma unroll
                for (int j = 0; j < 4; ++j)
                    acc[i][j] = fmaf(a[i], bb[j], acc[i][j]);
        }
        __syncthreads();
    }
    #pragma unroll
    for (int i = 0; i < 4; ++i) {
        const int rr = row0 + ty*4 + i;
        #pragma unroll
        for (int j = 0; j < 4; ++j)
            C[(size_t)rr*N + col0 + tx*4 + j] = acc[i][j];
    }
}

// ---------------------------------------------------------------------------
__global__ __launch_bounds__(256) void reduce_bias_act(
    const float* __restrict__ pbuf, const float* __restrict__ bias,
    float* __restrict__ C, int S, int relu)
{
    const int idx4 = (blockIdx.x * 256 + threadIdx.x) * 4;
    const int col = idx4 & (HID - 1);
    float4 a = *(const float4*)&pbuf[idx4];
    for (int s = 1; s < S; ++s) {
        const float4 b = *(const float4*)&pbuf[(size_t)s*BATCH*HID + idx4];
        a.x += b.x; a.y += b.y; a.z += b.z; a.w += b.w;
    }
    const float4 bi = *(const float4*)&bias[col];
    a.x += bi.x; a.y += bi.y; a.z += bi.z; a.w += bi.w;
    if (relu) {
        a.x = fmaxf(a.x, 0.0f); a.y = fmaxf(a.y, 0.0f);
        a.z = fmaxf(a.z, 0.0f); a.w = fmaxf(a.w, 0.0f);
    }
    *(float4*)&C[idx4] = a;
}

// ---------------------------------------------------------------------------
__global__ __launch_bounds__(64) void z_kernel(
    const float* __restrict__ h, const float* __restrict__ wmu,
    const float* __restrict__ bmu, const float* __restrict__ wlv,
    const float* __restrict__ blv, const float* __restrict__ eps,
    float* __restrict__ dec_in)
{
    const int b = blockIdx.x, lane = threadIdx.x;
    float a0 = 0, a1 = 0, a2 = 0, a3 = 0;
    for (int hh = lane; hh < HID; hh += 64) {
        float v = h[b*HID + hh];
        a0 = fmaf(v, wmu[hh*2 + 0], a0);
        a1 = fmaf(v, wmu[hh*2 + 1], a1);
        a2 = fmaf(v, wlv[hh*2 + 0], a2);
        a3 = fmaf(v, wlv[hh*2 + 1], a3);
    }
    #pragma unroll
    for (int off = 32; off; off >>= 1) {
        a0 += __shfl_down(a0, off);
        a1 += __shfl_down(a1, off);
        a2 += __shfl_down(a2, off);
        a3 += __shfl_down(a3, off);
    }
    if (lane == 0) {
        float mu0 = a0 + bmu[0], mu1 = a1 + bmu[1];
        float lv0 = a2 + blv[0], lv1 = a3 + blv[1];
        dec_in[b*DECIN + 0] = fmaf(expf(0.5f*lv0), eps[b*2 + 0], mu0);
        dec_in[b*DECIN + 1] = fmaf(expf(0.5f*lv1), eps[b*2 + 1], mu1);
    }
}

// ---------------------------------------------------------------------------
__global__ __launch_bounds__(64) void out8_kernel(
    const float* __restrict__ h, const float* __restrict__ w3,
    const float* __restrict__ b3, float* __restrict__ nn_out)
{
    const int b = blockIdx.x, lane = threadIdx.x;
    float acc[8] = {};
    for (int hh = lane; hh < HID; hh += 64) {
        float v = h[b*HID + hh];
        #pragma unroll
        for (int j = 0; j < 8; ++j) acc[j] = fmaf(v, w3[hh*8 + j], acc[j]);
    }
    #pragma unroll
    for (int j = 0; j < 8; ++j)
        #pragma unroll
        for (int off = 32; off; off >>= 1) acc[j] += __shfl_down(acc[j], off);
    if (lane == 0)
        for (int j = 0; j < 8; ++j) nn_out[b*8 + j] = acc[j] + b3[j];
}

// ---------------------------------------------------------------------------
// Batched ADMM solver, register-resident bases:
//  threads 0..99   (A): own timepoint t; P/Pd/Pdd rows + obstacle positions
//                       preloaded in registers; write 7 residual rows.
//  threads 100..253 (B): own (k, dot, chunk); 52-float basis column window in
//                       registers; read residual window as 13x ds_read_b128.
//  threads 0..21 (B2/C): lambda/lincost assembly + KKT solve via inverse.
// LDS traffic per iter: ~90 wave-issues (was ~620 -> LDS-bound at 119us).
// ---------------------------------------------------------------------------
#define DOT11(bb, a0, a1, a2) \
    fmaf(bb[0],a0.x, fmaf(bb[1],a0.y, fmaf(bb[2],a0.z, fmaf(bb[3],a0.w, \
    fmaf(bb[4],a1.x, fmaf(bb[5],a1.y, fmaf(bb[6],a1.z, fmaf(bb[7],a1.w, \
    fmaf(bb[8],a2.x, fmaf(bb[9],a2.y, bb[10]*a2.z))))))))))

__global__ __launch_bounds__(256) void solver_kernel(
    const float* __restrict__ nn_out, const float* __restrict__ inp,
    const float* __restrict__ ise, const float* __restrict__ yub_p,
    const float* __restrict__ ylb_p,
    const float* __restrict__ Pg, const float* __restrict__ Pdg,
    const float* __restrict__ Pddg,
    const float* __restrict__ ws, float* __restrict__ out)
{
    __shared__ __align__(16) float rows[7][104];   // residuals (t-padded to 104)
    __shared__ float part[NVAR][16];               // B partials [k][dot*2+chunk]
    __shared__ __align__(16) float cxb[2][12], cyb[2][12];
    __shared__ float lx[NVAR], ly[NVAR], cbx[NVAR], cby[NVAR];
    __shared__ float linx[NVAR], liny[NVAR];
    __shared__ float i2x[196], i2y[225], Qx[121], Qy[121];
    __shared__ float obs[4][NOBS];
    __shared__ float nn[8], lcx[NVAR], lcy[NVAR];

    const int b = blockIdx.x, tid = threadIdx.x;

    // ---- stage small constants ----
    for (int i = tid; i < 196; i += 256) i2x[i] = ws[WS_INV2X + i];
    for (int i = tid; i < 225; i += 256) i2y[i] = ws[WS_INV2Y + i];
    for (int i = tid; i < 121; i += 256) { Qx[i] = ws[WS_QX + i]; Qy[i] = ws[WS_QY + i]; }
    float* i1x = &rows[0][0];          // 196 (aliased; consumed before loop)
    float* i1y = &rows[0][0] + 200;    // 225
    for (int i = tid; i < 196; i += 256) i1x[i] = ws[WS_INV1X + i];
    for (int i = tid; i < 225; i += 256) i1y[i] = ws[WS_INV1Y + i];
    if (tid < 40) {
        const int o = tid % 10, w = tid / 10;
        obs[w][o] = inp[b*INPD + 5 + w + 5*o];
    }
    if (tid < 8) nn[tid] = nn_out[b*8 + tid];

    // ---- register preloads (iteration-invariant) ----
    const bool isA = (tid < NUMPT);
    const bool isB = (tid >= 100 && tid < 254);
    float bP[NVAR], bPd[NVAR], bPdd[NVAR];     // A: basis row at t
    float xo[NOBS], yo[NOBS];                  // A: obstacle positions at t
    float breg[52];                            // B: basis column window
    int bk = 0, bu = 0, bc0 = 0, brow = 0;
    const float tt = (float)tid * (T_FIN_C / 99.0f);

    if (isA) {
        #pragma unroll
        for (int k = 0; k < NVAR; ++k) {
            bP[k]   = Pg[tid*NVAR + k];
            bPd[k]  = Pdg[tid*NVAR + k];
            bPdd[k] = Pddg[tid*NVAR + k];
        }
    }
    if (isB) {
        const int j = tid - 100;
        bk = j / 14; bu = j % 14;
        const int dot = bu >> 1;
        bc0 = (bu & 1) * 52;
        brow = dot;
        const float* Mg = (dot == 1 || dot == 4) ? Pddg
                        : (dot == 2 || dot == 5) ? Pdg : Pg;
        #pragma unroll
        for (int i = 0; i < 52; ++i) {
            const int t = bc0 + i;
            breg[i] = (t < NUMPT) ? Mg[t*NVAR + bk] : 0.0f;
        }
    }

    const float vx0 = ise[b*4 + 2], vy0 = ise[b*4 + 3];
    const float yub = yub_p[b], ylb = ylb_p[b];
    __syncthreads();

    if (isA) {   // obstacle trajectories (constant over iterations)
        #pragma unroll
        for (int o = 0; o < NOBS; ++o) {
            xo[o] = fmaf(obs[2][o], tt, obs[0][o]);
            yo[o] = fmaf(obs[3][o], tt, obs[1][o]);
        }
    }

    // ---- lincost + c_bar init ----
    if (tid < NVAR) {
        float sx_ = 0.0f, sy_ = 0.0f;
        #pragma unroll
        for (int c = 0; c < 4; ++c) {
            sx_ = fmaf(nn[c],     ws[WS_SVD + c*11 + tid], sx_);
            sy_ = fmaf(nn[4 + c], ws[WS_SPD + c*11 + tid], sy_);
        }
        lcx[tid] = RHO_V_C * K_P_V_C * sx_;
        lcy[tid] = RHO_OFFSET_C * K_P_C * sy_;
    }
    __syncthreads();
    if (tid < NVAR) {
        const int k = tid;
        float ax = vx0 * i1x[k*14 + 12];
        float ay = vy0 * i1y[k*15 + 12];
        #pragma unroll
        for (int j = 0; j < NVAR; ++j) {
            ax = fmaf(-lcx[j], i1x[k*14 + j], ax);
            ay = fmaf(-lcy[j], i1y[k*15 + j], ay);
        }
        cbx[k] = ax; cby[k] = ay;
        cxb[0][k] = ax; cyb[0][k] = ay;
        lx[k] = 0.0f; ly[k] = 0.0f;
    }
    __syncthreads();
    // zero residual tail pads + c pads (after i1 alias is dead)
    if (tid < 28) rows[tid / 4][100 + (tid & 3)] = 0.0f;
    if (tid == 28) { cxb[0][11] = 0.0f; cxb[1][11] = 0.0f; }
    if (tid == 29) { cyb[0][11] = 0.0f; cyb[1][11] = 0.0f; }
    __syncthreads();

    int cur = 0;
    for (int it = 0; it < MAXIT; ++it) {
        // -------- phase A --------
        if (isA) {
            const int t = tid;
            const float4 x0 = *(const float4*)&cxb[cur][0];
            const float4 x1 = *(const float4*)&cxb[cur][4];
            const float4 x2 = *(const float4*)&cxb[cur][8];
            const float4 y0 = *(const float4*)&cyb[cur][0];
            const float4 y1 = *(const float4*)&cyb[cur][4];
            const float4 y2 = *(const float4*)&cyb[cur][8];
            const float px   = DOT11(bP,   x0, x1, x2);
            const float py   = DOT11(bP,   y0, y1, y2);
            const float pxd  = DOT11(bPd,  x0, x1, x2);
            const float pyd  = DOT11(bPd,  y0, y1, y2);
            const float pxdd = DOT11(bPdd, x0, x1, x2);
            const float pydd = DOT11(bPdd, y0, y1, y2);

            float srx = 0.0f, sry = 0.0f;
            #pragma unroll
            for (int o = 0; o < NOBS; ++o) {
                const float wc = px - xo[o], wsv = py - yo[o];
                const float aw = A_OBS_C * wsv, bw = B_OBS_C * wc;
                const float r2 = aw*aw + bw*bw;
                float ca, sa;
                if (r2 > 0.0f) { const float ri = rsqrtf(r2); ca = bw*ri; sa = aw*ri; }
                else           { ca = 1.0f; sa = 0.0f; }
                const float c1 = RHO_OBS_C * (A_OBS_C*A_OBS_C*ca*ca + B_OBS_C*B_OBS_C*sa*sa);
                const float c2 = RHO_OBS_C * (A_OBS_C*wc*ca + B_OBS_C*wsv*sa);
                const float d_o = fmaxf(1.0f, c2 / c1);
                srx += wc - A_OBS_C * d_o * ca;
                sry += wsv - B_OBS_C * d_o * sa;
            }
            // velocity projection
            float cv, sv, rv;
            const float rv2 = pxd*pxd + pyd*pyd;
            if (rv2 > 0.0f) { const float ri = rsqrtf(rv2); rv = rv2*ri; cv = pxd*ri; sv = pyd*ri; }
            else            { rv = 0.0f; cv = 1.0f; sv = 0.0f; }
            const float dv = fminf(fmaxf(rv, V_MIN_C), V_MAX_C);
            // acceleration projection
            float caa, saa, ra;
            const float ra2 = pxdd*pxdd + pydd*pydd;
            if (ra2 > 0.0f) { const float ri = rsqrtf(ra2); ra = ra2*ri; caa = pxdd*ri; saa = pydd*ri; }
            else            { ra = 0.0f; caa = 1.0f; saa = 0.0f; }
            const float da = fminf(ra, A_MAX_C);

            rows[0][t] = srx;                 // SX  (· P)
            rows[1][t] = pxdd - da*caa;       // AX  (· Pdd)
            rows[2][t] = pxd  - dv*cv;        // VX  (· Pd)
            rows[3][t] = sry;                 // SY  (· P)
            rows[4][t] = pydd - da*saa;       // AY  (· Pdd)
            rows[5][t] = pyd  - dv*sv;        // VY  (· Pd)
            rows[6][t] = fmaxf(0.0f, py - yub) - fmaxf(0.0f, ylb - py); // LN (· P)
        }
        __syncthreads();

        // -------- phase B: 154 dots, b128 residual reads, reg basis --------
        if (isB) {
            const float* rp = &rows[brow][bc0];
            float s = 0.0f;
            #pragma unroll
            for (int i4 = 0; i4 < 13; ++i4) {
                const float4 r4 = *(const float4*)&rp[i4*4];
                s = fmaf(r4.x, breg[4*i4 + 0], s);
                s = fmaf(r4.y, breg[4*i4 + 1], s);
                s = fmaf(r4.z, breg[4*i4 + 2], s);
                s = fmaf(r4.w, breg[4*i4 + 3], s);
            }
            part[bk][bu] = s;
        }
        __syncthreads();

        // -------- phase B2 --------
        if (tid < 22) {
            const int k = (tid < 11) ? tid : tid - 11;
            if (tid < 11) {
                float s = part[k][0] + part[k][1] + part[k][2]
                        + part[k][3] + part[k][4] + part[k][5];
                const float ux = RHO_OBS_C * s;
                float q = 0.0f;
                #pragma unroll
                for (int j = 0; j < NVAR; ++j) q = fmaf(Qx[k*11 + j], cxb[cur][j], q);
                const float l = lx[k];
                lx[k] = l - ux;
                linx[k] = -l + 2.0f*ux - RHO_PROJ_C*cbx[k] - q;
            } else {
                float s = part[k][6] + part[k][7] + part[k][8] + part[k][9]
                        + part[k][10] + part[k][11] + part[k][12] + part[k][13];
                const float uy = RHO_OBS_C * s;
                float q = 0.0f;
                #pragma unroll
                for (int j = 0; j < NVAR; ++j) q = fmaf(Qy[k*11 + j], cyb[cur][j], q);
                const float l = ly[k];
                ly[k] = l - uy;
                liny[k] = -l + 2.0f*uy - RHO_PROJ_C*cby[k] - q;
            }
        }
        __syncthreads();

        // -------- phase C --------
        if (tid < 22) {
            const int k = (tid < 11) ? tid : tid - 11;
            if (tid < 11) {
                float a = vx0 * i2x[k*14 + 12];
                #pragma unroll
                for (int j = 0; j < NVAR; ++j) a = fmaf(-linx[j], i2x[k*14 + j], a);
                cxb[cur ^ 1][k] = a;
            } else {
                float a = vy0 * i2y[k*15 + 12];
                #pragma unroll
                for (int j = 0; j < NVAR; ++j) a = fmaf(-liny[j], i2y[k*15 + j], a);
                cyb[cur ^ 1][k] = a;
            }
        }
        cur ^= 1;
        __syncthreads();
    }

    if (tid < NVAR) {
        out[b*22 + tid]      = cxb[cur][tid];
        out[b*22 + 11 + tid] = cyb[cur][tid];
    }
}

// ---------------------------------------------------------------------------
extern "C" void kernel_launch(void* const* d_in, const int* in_sizes, int n_in,
                              void* d_out, int out_size, void* d_ws, size_t ws_size,
                              hipStream_t stream)
{
    (void)in_sizes; (void)n_in; (void)out_size;
    const float* inp    = (const float*)d_in[0];
    const float* ise    = (const float*)d_in[1];
    const float* traj   = (const float*)d_in[2];
    const float* yub    = (const float*)d_in[3];
    const float* ylb    = (const float*)d_in[4];
    const float* eps    = (const float*)d_in[5];
    const float* enc_w1 = (const float*)d_in[6];
    const float* enc_b1 = (const float*)d_in[7];
    const float* enc_w2 = (const float*)d_in[8];
    const float* enc_b2 = (const float*)d_in[9];
    const float* wmu    = (const float*)d_in[10];
    const float* bmu    = (const float*)d_in[11];
    const float* wlv    = (const float*)d_in[12];
    const float* blv    = (const float*)d_in[13];
    const float* dec_w1 = (const float*)d_in[14];
    const float* dec_b1 = (const float*)d_in[15];
    const float* dec_w2 = (const float*)d_in[16];
    const float* dec_b2 = (const float*)d_in[17];
    const float* dec_w3 = (const float*)d_in[18];
    const float* dec_b3 = (const float*)d_in[19];
    const float* P      = (const float*)d_in[20];
    const float* Pd     = (const float*)d_in[21];
    const float* Pdd    = (const float*)d_in[22];
    const float* mean   = (const float*)d_in[23];
    const float* stdv   = (const float*)d_in[24];

    float* ws     = (float*)d_ws;
    float* enc_in = ws + WS_BIG;                     // B x 255
    float* dec_in = enc_in + (size_t)BATCH * ENCIN;  // B x 57
    float* hA     = dec_in + (size_t)BATCH * DECIN;  // B x 1024
    float* hB     = hA + (size_t)BATCH * HID;        // B x 1024
    float* nn     = hB + (size_t)BATCH * HID;        // B x 8
    float* pbuf   = nn + (size_t)BATCH * 8;          // S x (B x 1024)
    float* outf   = (float*)d_out;

    const size_t base_bytes = ((size_t)(pbuf - ws)) * sizeof(float);
    const size_t avail = (ws_size > base_bytes) ? ws_size - base_bytes : 0;
    const size_t one = (size_t)BATCH * HID * sizeof(float);
    int Smax = (int)(avail / one);
    if (Smax > 8) Smax = 8;
    if (Smax < 1) Smax = 1;

    auto S_of = [&](int K) {
        int s = (K + 15) / 16;           // at most one 16-tile per chunk
        if (s > Smax) s = Smax;
        return s;
    };
    auto chunk_of = [&](int K, int S) { return ((K + S - 1) / S + 15) & ~15; };

    precompute_kernel<<<4, 256, 0, stream>>>(P, Pd, Pdd, ws);
    prep_kernel<<<BATCH, 256, 0, stream>>>(inp, traj, mean, stdv, enc_in, dec_in);

    const int rblocks = BATCH * HID / 4 / 256;   // 1024

    int S1 = S_of(ENCIN);
    gemm_splitk<<<dim3(HID/64, BATCH/64, S1), 256, 0, stream>>>(
        enc_in, enc_w1, pbuf, BATCH, HID, ENCIN, chunk_of(ENCIN, S1));
    reduce_bias_act<<<rblocks, 256, 0, stream>>>(pbuf, enc_b1, hA, S1, 1);

    int S2 = S_of(HID);
    gemm_splitk<<<dim3(HID/64, BATCH/64, S2), 256, 0, stream>>>(
        hA, enc_w2, pbuf, BATCH, HID, HID, chunk_of(HID, S2));
    reduce_bias_act<<<rblocks, 256, 0, stream>>>(pbuf, enc_b2, hB, S2, 1);

    z_kernel<<<BATCH, 64, 0, stream>>>(hB, wmu, bmu, wlv, blv, eps, dec_in);

    int S3 = S_of(DECIN);
    gemm_splitk<<<dim3(HID/64, BATCH/64, S3), 256, 0, stream>>>(
        dec_in, dec_w1, pbuf, BATCH, HID, DECIN, chunk_of(DECIN, S3));
    reduce_bias_act<<<rblocks, 256, 0, stream>>>(pbuf, dec_b1, hA, S3, 1);

    int S4 = S_of(HID);
    gemm_splitk<<<dim3(HID/64, BATCH/64, S4), 256, 0, stream>>>(
        hA, dec_w2, pbuf, BATCH, HID, HID, chunk_of(HID, S4));
    reduce_bias_act<<<rblocks, 256, 0, stream>>>(pbuf, dec_b2, hB, S4, 1);

    out8_kernel<<<BATCH, 64, 0, stream>>>(hB, dec_w3, dec_b3, nn);
    solver_kernel<<<BATCH, 256, 0, stream>>>(nn, inp, ise, yub, ylb,
                                             P, Pd, Pdd, ws, outf);
}

// Round 5
// 312.640 us; speedup vs baseline: 1.2873x; 1.2873x over previous
//
#include <hip/hip_runtime.h>
#include <hip/hip_bf16.h>
#include <math.h>

// ---------------- problem constants ----------------
#define BATCH   1024
#define NUMPT   100
#define NVAR    11
#define NOBS    10
#define HID     1024
#define INPD    55
#define TRAJD   200

#define T_FIN_C   15.0f
#define K_P_C     20.0f
#define K_D_C     8.944271909999159f   // 2*sqrt(20)
#define K_P_V_C   20.0f
#define A_OBS_C   8.0f
#define B_OBS_C   4.2f
#define RHO_V_C      1.0f
#define RHO_PROJ_C   1.0f
#define RHO_LANE_C   100.0f
#define RHO_OBS_C    100.0f
#define RHO_OFFSET_C 1.0f
#define RHO_INEQ_C   100.0f
#define V_MIN_C   0.1f
#define V_MAX_C   30.0f
#define A_MAX_C   8.0f
#define MAXIT     20

// workspace layout (float offsets)
#define WS_INV1X  0      // 14x14
#define WS_INV1Y  256    // 15x15
#define WS_INV2X  512    // 14x14
#define WS_INV2Y  768    // 15x15
#define WS_SVD    1024   // 4x11 chunk-summed A_vd
#define WS_SPD    1088   // 4x11 chunk-summed A_pd
#define WS_QX     1152   // 11x11
#define WS_QY     1280   // 11x11
#define WS_R2X    1408   // 11x11  inv2x[:11,:11] @ Qx
#define WS_R2Y    1536   // 11x11
#define WS_BIG    2048

typedef __bf16 bf16x8 __attribute__((ext_vector_type(8)));
typedef float  f32x4  __attribute__((ext_vector_type(4)));

// ---------------------------------------------------------------------------
// Precompute: KKT matrices + inverses (GJ w/ partial pivoting — cost1_x's
// 11x11 block is singular), Qx/Qy, R2 = inv2[:11,:11]@Q, chunk-summed
// A_vd/A_pd. grid = 4 blocks, 256 threads.
// ---------------------------------------------------------------------------
__global__ __launch_bounds__(256) void precompute_kernel(
    const float* __restrict__ Pg, const float* __restrict__ Pdg,
    const float* __restrict__ Pddg, float* __restrict__ ws)
{
    __shared__ float sP[NUMPT*NVAR], sPd[NUMPT*NVAR], sPdd[NUMPT*NVAR];
    __shared__ float aug[15][31];
    __shared__ float fcol[15];
    __shared__ float sQ[121];
    __shared__ float s_pivinv;
    __shared__ int   s_pidx;
    const int tid = threadIdx.x, bid = blockIdx.x;

    for (int i = tid; i < NUMPT*NVAR; i += blockDim.x) {
        sP[i] = Pg[i]; sPd[i] = Pdg[i]; sPdd[i] = Pddg[i];
    }
    for (int i = tid; i < 15*31; i += blockDim.x) (&aug[0][0])[i] = 0.0f;
    __syncthreads();

    const int N = (bid == 0 || bid == 2) ? 14 : 15;

    if (tid < 121) {
        const int i = tid / 11, j = tid % 11;
        float s = 0.0f;
        if (bid == 0) {
            for (int t = 0; t < NUMPT; ++t) {
                float pdd_i = sPdd[t*NVAR+i], pdd_j = sPdd[t*NVAR+j];
                float av_i = pdd_i - K_P_V_C * sPd[t*NVAR+i];
                float av_j = pdd_j - K_P_V_C * sPd[t*NVAR+j];
                s += pdd_i*pdd_j + RHO_V_C * av_i*av_j;
            }
        } else if (bid == 1) {
            for (int t = 0; t < NUMPT; ++t) {
                float pdd_i = sPdd[t*NVAR+i], pdd_j = sPdd[t*NVAR+j];
                float ap_i = pdd_i - K_P_C*sP[t*NVAR+i] - K_D_C*sPd[t*NVAR+i];
                float ap_j = pdd_j - K_P_C*sP[t*NVAR+j] - K_D_C*sPd[t*NVAR+j];
                s += pdd_i*pdd_j + RHO_OFFSET_C * ap_i*ap_j;
            }
        } else {
            float obs_w = RHO_OBS_C * (float)NOBS;
            if (bid == 3) obs_w += RHO_LANE_C * 2.0f;
            for (int t = 0; t < NUMPT; ++t) {
                float p_i = sP[t*NVAR+i],   p_j = sP[t*NVAR+j];
                float pd_i = sPd[t*NVAR+i], pd_j = sPd[t*NVAR+j];
                float pdd_i = sPdd[t*NVAR+i], pdd_j = sPdd[t*NVAR+j];
                s += obs_w*p_i*p_j + RHO_INEQ_C*(pdd_i*pdd_j + pd_i*pd_j);
            }
            if (i == j) s += RHO_PROJ_C;
        }
        aug[i][j] = s;
    }
    if (tid < 11) {
        const int i = tid;
        float a0 = sP[i], a1 = sPd[i], a2 = sPdd[i];
        aug[i][11] = a0; aug[11][i] = a0;
        aug[i][12] = a1; aug[12][i] = a1;
        aug[i][13] = a2; aug[13][i] = a2;
        if (N == 15) { float a3 = sPd[99*NVAR + i]; aug[i][14] = a3; aug[14][i] = a3; }
    }
    if (tid < N) aug[tid][N + tid] = 1.0f;

    if (bid == 0 && tid < 44) {
        const int c = tid / 11, k = tid % 11;
        float sv = 0.0f, sp = 0.0f;
        for (int t = 25*c; t < 25*c + 25; ++t) {
            float p = sP[t*NVAR+k], pd = sPd[t*NVAR+k], pdd = sPdd[t*NVAR+k];
            sv += pdd - K_P_V_C * pd;
            sp += pdd - K_P_C * p - K_D_C * pd;
        }
        ws[WS_SVD + tid] = sv;
        ws[WS_SPD + tid] = sp;
    }
    __syncthreads();

    if ((bid == 2 || bid == 3) && tid < 121) {
        float v = aug[tid/11][tid%11];
        if (tid/11 == tid%11) v -= RHO_PROJ_C;
        sQ[tid] = v;
        ws[(bid == 2 ? WS_QX : WS_QY) + tid] = v;
    }

    for (int k = 0; k < N; ++k) {
        if (tid == 0) {
            int p = k; float best = fabsf(aug[k][k]);
            for (int i = k+1; i < N; ++i) {
                float v = fabsf(aug[i][k]);
                if (v > best) { best = v; p = i; }
            }
            s_pidx = p;
        }
        __syncthreads();
        const int p = s_pidx;
        if (p != k && tid < 2*N) {
            float tmp = aug[k][tid]; aug[k][tid] = aug[p][tid]; aug[p][tid] = tmp;
        }
        __syncthreads();
        if (tid == 0) s_pivinv = 1.0f / aug[k][k];
        __syncthreads();
        if (tid < 2*N) aug[k][tid] *= s_pivinv;
        __syncthreads();
        if (tid < N) fcol[tid] = (tid == k) ? 0.0f : aug[tid][k];
        __syncthreads();
        for (int idx = tid; idx < N*2*N; idx += blockDim.x) {
            const int i = idx / (2*N), j = idx % (2*N);
            if (i != k) aug[i][j] = fmaf(-fcol[i], aug[k][j], aug[i][j]);
        }
        __syncthreads();
    }

    float* dst = ws + (bid == 0 ? WS_INV1X : bid == 1 ? WS_INV1Y
                      : bid == 2 ? WS_INV2X : WS_INV2Y);
    for (int idx = tid; idx < N*N; idx += blockDim.x)
        dst[idx] = aug[idx / N][N + idx % N];
    __syncthreads();

    // R2 = inv2[:11,:11] @ Q  (inverse sits in aug[:, N:2N])
    if ((bid == 2 || bid == 3) && tid < 121) {
        const int k = tid / 11, j = tid % 11;
        float a = 0.0f;
        #pragma unroll
        for (int m = 0; m < 11; ++m) a = fmaf(aug[k][N + m], sQ[m*11 + j], a);
        ws[(bid == 2 ? WS_R2X : WS_R2Y) + tid] = a;
    }
}

// ---------------------------------------------------------------------------
// Weight convert: Wt_bf16[N][Kp] = transpose(W fp32 [K][N]), zero-pad k>=K.
// ---------------------------------------------------------------------------
__global__ __launch_bounds__(256) void convert_wt(
    const float* __restrict__ W, __bf16* __restrict__ Wt, int K, int N, int Kp)
{
    const int idx = blockIdx.x * 256 + threadIdx.x;
    if (idx >= N * Kp) return;
    const int n = idx / Kp, k = idx - n * Kp;
    const float v = (k < K) ? W[(size_t)k * N + n] : 0.0f;
    Wt[idx] = (__bf16)v;
}

// ---------------------------------------------------------------------------
// Input prep -> bf16: enc_in [B][256] = [inp_n(55), traj(200), 0];
// dec_in [B][64] cols 2..56 = inp_n, 57..63 = 0 (cols 0..1 by z_kernel).
// ---------------------------------------------------------------------------
__global__ __launch_bounds__(256) void prep_bf(
    const float* __restrict__ inp, const float* __restrict__ traj,
    const float* __restrict__ mean, const float* __restrict__ stdv,
    __bf16* __restrict__ enc_in, __bf16* __restrict__ dec_in)
{
    __shared__ float sn[INPD];
    const int b = blockIdx.x, t = threadIdx.x;
    if (t < INPD) {
        const float v = (inp[b*INPD + t] - mean[t]) / stdv[t];
        sn[t] = v;
        enc_in[b*256 + t] = (__bf16)v;
    } else if (t < 255) {
        enc_in[b*256 + t] = (__bf16)traj[b*TRAJD + (t - INPD)];
    } else {
        enc_in[b*256 + 255] = (__bf16)0.0f;
    }
    __syncthreads();
    if (t >= 2 && t < 64)
        dec_in[b*64 + t] = (__bf16)((t < 57) ? sn[t - 2] : 0.0f);
}

// ---------------------------------------------------------------------------
// bf16 MFMA GEMM: C_bf16[1024][1024] = relu(A_bf16[1024][Kp] @ Wt^T + bias).
// Wt is [N][Kp] (pre-transposed). 64x64 tile, BK=64, 4 waves (each 32x32 via
// 2x2 mfma_f32_16x16x32_bf16), bias+ReLU fused in epilogue.
// ---------------------------------------------------------------------------
__global__ __launch_bounds__(256) void gemm_mfma(
    const __bf16* __restrict__ A, const __bf16* __restrict__ Wt,
    const float* __restrict__ bias, __bf16* __restrict__ C, int Kp)
{
    __shared__ __bf16 As[64][72];   // pad 72: 2-way (free) bank aliasing
    __shared__ __bf16 Bs[64][72];
    const int tid = threadIdx.x;
    const int lane = tid & 63, wv = tid >> 6;
    const int wm = (wv >> 1) * 32, wn = (wv & 1) * 32;
    const int ln = lane & 15, q = lane >> 4;
    const int row0 = blockIdx.y * 64, col0 = blockIdx.x * 64;
    const int lrow = tid >> 2, lc = tid & 3;

    f32x4 acc[2][2];
    #pragma unroll
    for (int i = 0; i < 2; ++i)
        #pragma unroll
        for (int j = 0; j < 2; ++j)
            acc[i][j] = (f32x4){0.0f, 0.0f, 0.0f, 0.0f};

    for (int k0 = 0; k0 < Kp; k0 += 64) {
        #pragma unroll
        for (int p = 0; p < 2; ++p) {
            const int cc = (lc + 4*p) * 8;
            *(bf16x8*)&As[lrow][cc] =
                *(const bf16x8*)&A[(size_t)(row0 + lrow) * Kp + k0 + cc];
            *(bf16x8*)&Bs[lrow][cc] =
                *(const bf16x8*)&Wt[(size_t)(col0 + lrow) * Kp + k0 + cc];
        }
        __syncthreads();
        #pragma unroll
        for (int kc = 0; kc < 2; ++kc) {
            const bf16x8 a0 = *(const bf16x8*)&As[wm + ln][kc*32 + q*8];
            const bf16x8 a1 = *(const bf16x8*)&As[wm + 16 + ln][kc*32 + q*8];
            const bf16x8 b0 = *(const bf16x8*)&Bs[wn + ln][kc*32 + q*8];
            const bf16x8 b1 = *(const bf16x8*)&Bs[wn + 16 + ln][kc*32 + q*8];
            acc[0][0] = __builtin_amdgcn_mfma_f32_16x16x32_bf16(a0, b0, acc[0][0], 0, 0, 0);
            acc[0][1] = __builtin_amdgcn_mfma_f32_16x16x32_bf16(a0, b1, acc[0][1], 0, 0, 0);
            acc[1][0] = __builtin_amdgcn_mfma_f32_16x16x32_bf16(a1, b0, acc[1][0], 0, 0, 0);
            acc[1][1] = __builtin_amdgcn_mfma_f32_16x16x32_bf16(a1, b1, acc[1][1], 0, 0, 0);
        }
        __syncthreads();
    }
    // epilogue: D col = lane&15, row = quad*4 + reg  [m89-verified mapping]
    #pragma unroll
    for (int ni = 0; ni < 2; ++ni) {
        const int col = col0 + wn + ni*16 + ln;
        const float bv = bias[col];
        #pragma unroll
        for (int mi = 0; mi < 2; ++mi) {
            #pragma unroll
            for (int r = 0; r < 4; ++r) {
                const int row = row0 + wm + mi*16 + q*4 + r;
                float v = acc[mi][ni][r] + bv;
                v = fmaxf(v, 0.0f);
                C[(size_t)row * HID + col] = (__bf16)v;
            }
        }
    }
}

// ---------------------------------------------------------------------------
__global__ __launch_bounds__(64) void z_kernel(
    const __bf16* __restrict__ h, const float* __restrict__ wmu,
    const float* __restrict__ bmu, const float* __restrict__ wlv,
    const float* __restrict__ blv, const float* __restrict__ eps,
    __bf16* __restrict__ dec_in)
{
    const int b = blockIdx.x, lane = threadIdx.x;
    float a0 = 0, a1 = 0, a2 = 0, a3 = 0;
    for (int hh = lane; hh < HID; hh += 64) {
        const float v = (float)h[b*HID + hh];
        a0 = fmaf(v, wmu[hh*2 + 0], a0);
        a1 = fmaf(v, wmu[hh*2 + 1], a1);
        a2 = fmaf(v, wlv[hh*2 + 0], a2);
        a3 = fmaf(v, wlv[hh*2 + 1], a3);
    }
    #pragma unroll
    for (int off = 32; off; off >>= 1) {
        a0 += __shfl_down(a0, off);
        a1 += __shfl_down(a1, off);
        a2 += __shfl_down(a2, off);
        a3 += __shfl_down(a3, off);
    }
    if (lane == 0) {
        const float mu0 = a0 + bmu[0], mu1 = a1 + bmu[1];
        const float lv0 = a2 + blv[0], lv1 = a3 + blv[1];
        dec_in[b*64 + 0] = (__bf16)fmaf(expf(0.5f*lv0), eps[b*2 + 0], mu0);
        dec_in[b*64 + 1] = (__bf16)fmaf(expf(0.5f*lv1), eps[b*2 + 1], mu1);
    }
}

// ---------------------------------------------------------------------------
__global__ __launch_bounds__(64) void out8_kernel(
    const __bf16* __restrict__ h, const float* __restrict__ w3,
    const float* __restrict__ b3, float* __restrict__ nn_out)
{
    const int b = blockIdx.x, lane = threadIdx.x;
    float acc[8] = {};
    for (int hh = lane; hh < HID; hh += 64) {
        const float v = (float)h[b*HID + hh];
        #pragma unroll
        for (int j = 0; j < 8; ++j) acc[j] = fmaf(v, w3[hh*8 + j], acc[j]);
    }
    #pragma unroll
    for (int j = 0; j < 8; ++j)
        #pragma unroll
        for (int off = 32; off; off >>= 1) acc[j] += __shfl_down(acc[j], off);
    if (lane == 0)
        for (int j = 0; j < 8; ++j) nn_out[b*8 + j] = acc[j] + b3[j];
}

// ---------------------------------------------------------------------------
// Wave-synchronous ADMM solver: ONE WAVE per batch element, 4 waves/block,
// 256 blocks (1 per CU). All cross-phase data flows through per-wave LDS
// regions with in-order DS semantics; 3 cheap lockstep barriers/iter.
// Per-lane registers: basis rows for its 1-2 timepoints, obstacle positions,
// lambda/c_bar (lanes 0..21). Phase C folded via R2 = inv2@Q (no Q matvec
// barrier).
// ---------------------------------------------------------------------------
#define DOT11(bb, a0, a1, a2) \
    fmaf(bb[0],a0.x, fmaf(bb[1],a0.y, fmaf(bb[2],a0.z, fmaf(bb[3],a0.w, \
    fmaf(bb[4],a1.x, fmaf(bb[5],a1.y, fmaf(bb[6],a1.z, fmaf(bb[7],a1.w, \
    fmaf(bb[8],a2.x, fmaf(bb[9],a2.y, bb[10]*a2.z))))))))))

__global__ __launch_bounds__(256) void solver_kernel(
    const float* __restrict__ nn_out, const float* __restrict__ inp,
    const float* __restrict__ ise, const float* __restrict__ yub_p,
    const float* __restrict__ ylb_p,
    const float* __restrict__ Pg, const float* __restrict__ Pdg,
    const float* __restrict__ Pddg,
    const float* __restrict__ ws, float* __restrict__ out)
{
    __shared__ __align__(16) float sBcol[3][11][108];   // [P,Pd,Pdd] columns, t-padded 0
    __shared__ float s_i2x[196], s_i2y[225], sR2x[121], sR2y[121];
    __shared__ __align__(16) float rowsW[4][7][104];    // per-wave residual rows
    __shared__ float dval[4][80];                       // per-wave 77 dots
    __shared__ __align__(16) float cxs[4][12], cys[4][12];
    __shared__ float wlin[4][24];
    __shared__ float obsS[4][4][10];

    const int tid = threadIdx.x;
    const int w = tid >> 6, lane = tid & 63;
    const int e = blockIdx.x * 4 + w;

    // ---- cooperative staging of shared constants ----
    for (int i = tid; i < 3*11*108; i += 256) {
        const int mat = i / 1188, rem = i - mat*1188;
        const int k = rem / 108, t = rem - k*108;
        const float* G = (mat == 0) ? Pg : (mat == 1 ? Pdg : Pddg);
        sBcol[mat][k][t] = (t < NUMPT) ? G[t*NVAR + k] : 0.0f;
    }
    for (int i = tid; i < 196; i += 256) s_i2x[i] = ws[WS_INV2X + i];
    for (int i = tid; i < 225; i += 256) s_i2y[i] = ws[WS_INV2Y + i];
    for (int i = tid; i < 121; i += 256) { sR2x[i] = ws[WS_R2X + i]; sR2y[i] = ws[WS_R2Y + i]; }
    if (lane < 40) obsS[w][lane/10][lane%10] = inp[e*INPD + 5 + (lane/10) + 5*(lane%10)];
    if (lane < 28) rowsW[w][lane >> 2][100 + (lane & 3)] = 0.0f;
    if (lane == 28) cxs[w][11] = 0.0f;
    if (lane == 29) cys[w][11] = 0.0f;

    // ---- per-lane register preloads (iteration-invariant) ----
    const int t1 = lane, t2 = lane + 64;
    float bP1[11], bPd1[11], bPdd1[11], bP2[11], bPd2[11], bPdd2[11];
    #pragma unroll
    for (int k = 0; k < NVAR; ++k) {
        bP1[k] = Pg[t1*NVAR+k]; bPd1[k] = Pdg[t1*NVAR+k]; bPdd1[k] = Pddg[t1*NVAR+k];
    }
    if (lane < 36) {
        #pragma unroll
        for (int k = 0; k < NVAR; ++k) {
            bP2[k] = Pg[t2*NVAR+k]; bPd2[k] = Pdg[t2*NVAR+k]; bPdd2[k] = Pddg[t2*NVAR+k];
        }
    } else {
        #pragma unroll
        for (int k = 0; k < NVAR; ++k) { bP2[k] = 0; bPd2[k] = 0; bPdd2[k] = 0; }
    }

    // phase-B dot assignments: dot d = r*11+k; r: 0 SX.P,1 AX.Pdd,2 VX.Pd,
    // 3 SY.P, 4 AY.Pdd, 5 VY.Pd, 6 LN.P
    const int d1 = lane;
    const int r1 = d1 / 11, k1 = d1 - 11*r1;
    const int d2c = (lane < 13) ? (64 + lane) : 76;
    const int r2 = d2c / 11, k2 = d2c - 11*r2;
    const int m1 = (r1==1||r1==4) ? 2 : ((r1==2||r1==5) ? 1 : 0);
    const int m2 = (r2==1||r2==4) ? 2 : ((r2==2||r2==5) ? 1 : 0);
    const float* colp1 = &sBcol[m1][k1][0];
    const float* colp2 = &sBcol[m2][k2][0];
    const float* rowp1 = &rowsW[w][r1][0];
    const float* rowp2 = &rowsW[w][r2][0];

    const float vx0 = ise[e*4 + 2], vy0 = ise[e*4 + 3];
    const float yub = yub_p[e], ylb = ylb_p[e];

    __syncthreads();

    // obstacle trajectories -> registers
    const float DT = T_FIN_C / 99.0f;
    float xo1[10], yo1[10], xo2[10], yo2[10];
    #pragma unroll
    for (int o = 0; o < NOBS; ++o) {
        xo1[o] = fmaf(obsS[w][2][o], t1*DT, obsS[w][0][o]);
        yo1[o] = fmaf(obsS[w][3][o], t1*DT, obsS[w][1][o]);
        xo2[o] = fmaf(obsS[w][2][o], t2*DT, obsS[w][0][o]);
        yo2[o] = fmaf(obsS[w][3][o], t2*DT, obsS[w][1][o]);
    }

    // ---- lincost broadcast + c_bar init ----
    if (lane < 11) {
        float s = 0;
        #pragma unroll
        for (int c = 0; c < 4; ++c)
            s = fmaf(nn_out[e*8 + c], ws[WS_SVD + c*11 + lane], s);
        wlin[w][lane] = RHO_V_C * K_P_V_C * s;
    } else if (lane < 22) {
        const int k = lane - 11;
        float s = 0;
        #pragma unroll
        for (int c = 0; c < 4; ++c)
            s = fmaf(nn_out[e*8 + 4 + c], ws[WS_SPD + c*11 + k], s);
        wlin[w][lane] = RHO_OFFSET_C * K_P_C * s;
    }
    __syncthreads();

    float lam = 0.0f, cb = 0.0f;
    if (lane < 11) {
        const int k = lane;
        float a = vx0 * ws[WS_INV1X + k*14 + 12];
        #pragma unroll
        for (int j = 0; j < NVAR; ++j)
            a = fmaf(-wlin[w][j], ws[WS_INV1X + k*14 + j], a);
        cb = a; cxs[w][k] = a;
    } else if (lane < 22) {
        const int k = lane - 11;
        float a = vy0 * ws[WS_INV1Y + k*15 + 12];
        #pragma unroll
        for (int j = 0; j < NVAR; ++j)
            a = fmaf(-wlin[w][11 + j], ws[WS_INV1Y + k*15 + j], a);
        cb = a; cys[w][k] = a;
    }
    __syncthreads();

    // ---- main loop ----
    for (int it = 0; it < MAXIT; ++it) {
        // -------- phase A: residual rows (1-2 timepoints per lane) --------
        {
            const float4 x0 = *(const float4*)&cxs[w][0];
            const float4 x1 = *(const float4*)&cxs[w][4];
            const float4 x2 = *(const float4*)&cxs[w][8];
            const float4 y0 = *(const float4*)&cys[w][0];
            const float4 y1 = *(const float4*)&cys[w][4];
            const float4 y2 = *(const float4*)&cys[w][8];

            auto pointA = [&](const float* bP, const float* bPd, const float* bPdd,
                              const float* xo, const float* yo, int t) {
                const float px   = DOT11(bP,   x0, x1, x2);
                const float py   = DOT11(bP,   y0, y1, y2);
                const float pxd  = DOT11(bPd,  x0, x1, x2);
                const float pyd  = DOT11(bPd,  y0, y1, y2);
                const float pxdd = DOT11(bPdd, x0, x1, x2);
                const float pydd = DOT11(bPdd, y0, y1, y2);
                float srx = 0.0f, sry = 0.0f;
                #pragma unroll
                for (int o = 0; o < NOBS; ++o) {
                    const float wc = px - xo[o], wsv = py - yo[o];
                    const float aw = A_OBS_C * wsv, bw = B_OBS_C * wc;
                    const float rr2 = aw*aw + bw*bw;
                    float ca, sa;
                    if (rr2 > 0.0f) { const float ri = rsqrtf(rr2); ca = bw*ri; sa = aw*ri; }
                    else            { ca = 1.0f; sa = 0.0f; }
                    const float c1 = RHO_OBS_C * (A_OBS_C*A_OBS_C*ca*ca + B_OBS_C*B_OBS_C*sa*sa);
                    const float c2 = RHO_OBS_C * (A_OBS_C*wc*ca + B_OBS_C*wsv*sa);
                    const float d_o = fmaxf(1.0f, c2 / c1);
                    srx += wc - A_OBS_C * d_o * ca;
                    sry += wsv - B_OBS_C * d_o * sa;
                }
                float cv, sv, rv;
                const float rv2 = pxd*pxd + pyd*pyd;
                if (rv2 > 0.0f) { const float ri = rsqrtf(rv2); rv = rv2*ri; cv = pxd*ri; sv = pyd*ri; }
                else            { rv = 0.0f; cv = 1.0f; sv = 0.0f; }
                const float dv = fminf(fmaxf(rv, V_MIN_C), V_MAX_C);
                float caa, saa, ra;
                const float ra2 = pxdd*pxdd + pydd*pydd;
                if (ra2 > 0.0f) { const float ri = rsqrtf(ra2); ra = ra2*ri; caa = pxdd*ri; saa = pydd*ri; }
                else            { ra = 0.0f; caa = 1.0f; saa = 0.0f; }
                const float da = fminf(ra, A_MAX_C);
                rowsW[w][0][t] = srx;
                rowsW[w][1][t] = pxdd - da*caa;
                rowsW[w][2][t] = pxd  - dv*cv;
                rowsW[w][3][t] = sry;
                rowsW[w][4][t] = pydd - da*saa;
                rowsW[w][5][t] = pyd  - dv*sv;
                rowsW[w][6][t] = fmaxf(0.0f, py - yub) - fmaxf(0.0f, ylb - py);
            };
            pointA(bP1, bPd1, bPdd1, xo1, yo1, t1);
            if (lane < 36) pointA(bP2, bPd2, bPdd2, xo2, yo2, t2);
        }
        __syncthreads();

        // -------- phase B: 77 full dots (1-2 per lane), b128 reads --------
        {
            float s = 0.0f;
            #pragma unroll
            for (int i = 0; i < 26; ++i) {
                const float4 rr = *(const float4*)&rowp1[i*4];
                const float4 cc = *(const float4*)&colp1[i*4];
                s = fmaf(rr.x, cc.x, s); s = fmaf(rr.y, cc.y, s);
                s = fmaf(rr.z, cc.z, s); s = fmaf(rr.w, cc.w, s);
            }
            dval[w][d1] = s;
            if (lane < 13) {
                float s2 = 0.0f;
                #pragma unroll
                for (int i = 0; i < 26; ++i) {
                    const float4 rr = *(const float4*)&rowp2[i*4];
                    const float4 cc = *(const float4*)&colp2[i*4];
                    s2 = fmaf(rr.x, cc.x, s2); s2 = fmaf(rr.y, cc.y, s2);
                    s2 = fmaf(rr.z, cc.z, s2); s2 = fmaf(rr.w, cc.w, s2);
                }
                dval[w][64 + lane] = s2;
            }
        }
        __syncthreads();

        // -------- phase C: lambda + KKT solve (intra-wave, in-order DS) ----
        if (lane < 22) {
            const int k = (lane < 11) ? lane : lane - 11;
            float u;
            if (lane < 11)
                u = RHO_OBS_C * (dval[w][k] + dval[w][11 + k] + dval[w][22 + k]);
            else
                u = RHO_OBS_C * (dval[w][33 + k] + dval[w][44 + k]
                               + dval[w][55 + k] + dval[w][66 + k]);
            wlin[w][lane] = 2.0f*u - lam - cb;
            lam -= u;
        }
        __builtin_amdgcn_wave_barrier();
        if (lane < 22) {
            const int k = (lane < 11) ? lane : lane - 11;
            if (lane < 11) {
                float a = vx0 * s_i2x[k*14 + 12];
                #pragma unroll
                for (int j = 0; j < NVAR; ++j) {
                    a = fmaf(-wlin[w][j], s_i2x[k*14 + j], a);
                    a = fmaf(sR2x[k*11 + j], cxs[w][j], a);
                }
                cxs[w][k] = a;
            } else {
                float a = vy0 * s_i2y[k*15 + 12];
                #pragma unroll
                for (int j = 0; j < NVAR; ++j) {
                    a = fmaf(-wlin[w][11 + j], s_i2y[k*15 + j], a);
                    a = fmaf(sR2y[k*11 + j], cys[w][j], a);
                }
                cys[w][k] = a;
            }
        }
        __syncthreads();
    }

    if (lane < NVAR) {
        out[e*22 + lane]      = cxs[w][lane];
        out[e*22 + 11 + lane] = cys[w][lane];
    }
}

// ---------------------------------------------------------------------------
extern "C" void kernel_launch(void* const* d_in, const int* in_sizes, int n_in,
                              void* d_out, int out_size, void* d_ws, size_t ws_size,
                              hipStream_t stream)
{
    (void)in_sizes; (void)n_in; (void)out_size; (void)ws_size;
    const float* inp    = (const float*)d_in[0];
    const float* ise    = (const float*)d_in[1];
    const float* traj   = (const float*)d_in[2];
    const float* yub    = (const float*)d_in[3];
    const float* ylb    = (const float*)d_in[4];
    const float* eps    = (const float*)d_in[5];
    const float* enc_w1 = (const float*)d_in[6];
    const float* enc_b1 = (const float*)d_in[7];
    const float* enc_w2 = (const float*)d_in[8];
    const float* enc_b2 = (const float*)d_in[9];
    const float* wmu    = (const float*)d_in[10];
    const float* bmu    = (const float*)d_in[11];
    const float* wlv    = (const float*)d_in[12];
    const float* blv    = (const float*)d_in[13];
    const float* dec_w1 = (const float*)d_in[14];
    const float* dec_b1 = (const float*)d_in[15];
    const float* dec_w2 = (const float*)d_in[16];
    const float* dec_b2 = (const float*)d_in[17];
    const float* dec_w3 = (const float*)d_in[18];
    const float* dec_b3 = (const float*)d_in[19];
    const float* P      = (const float*)d_in[20];
    const float* Pd     = (const float*)d_in[21];
    const float* Pdd    = (const float*)d_in[22];
    const float* mean   = (const float*)d_in[23];
    const float* stdv   = (const float*)d_in[24];

    float* ws   = (float*)d_ws;
    float* nn   = ws + WS_BIG;                        // 1024 x 8 fp32
    __bf16* bfb = (__bf16*)(ws + WS_BIG + BATCH*8);
    __bf16* enc_in = bfb;                             // 1024 x 256
    __bf16* dec_in = enc_in + (size_t)BATCH*256;      // 1024 x 64
    __bf16* hA     = dec_in + (size_t)BATCH*64;       // 1024 x 1024
    __bf16* hB     = hA + (size_t)BATCH*HID;          // 1024 x 1024
    __bf16* wt1    = hB + (size_t)BATCH*HID;          // 1024 x 256
    __bf16* wt2    = wt1 + (size_t)HID*256;           // 1024 x 1024
    __bf16* wt3    = wt2 + (size_t)HID*HID;           // 1024 x 64
    __bf16* wt4    = wt3 + (size_t)HID*64;            // 1024 x 1024
    float* outf = (float*)d_out;

    precompute_kernel<<<4, 256, 0, stream>>>(P, Pd, Pdd, ws);

    convert_wt<<<(HID*256)/256, 256, 0, stream>>>(enc_w1, wt1, 255, HID, 256);
    convert_wt<<<(HID*HID)/256, 256, 0, stream>>>(enc_w2, wt2, HID, HID, HID);
    convert_wt<<<(HID*64)/256, 256, 0, stream>>>(dec_w1, wt3, 57, HID, 64);
    convert_wt<<<(HID*HID)/256, 256, 0, stream>>>(dec_w2, wt4, HID, HID, HID);

    prep_bf<<<BATCH, 256, 0, stream>>>(inp, traj, mean, stdv, enc_in, dec_in);

    dim3 g(16, 16);
    gemm_mfma<<<g, 256, 0, stream>>>(enc_in, wt1, enc_b1, hA, 256);
    gemm_mfma<<<g, 256, 0, stream>>>(hA, wt2, enc_b2, hB, 1024);
    z_kernel<<<BATCH, 64, 0, stream>>>(hB, wmu, bmu, wlv, blv, eps, dec_in);
    gemm_mfma<<<g, 256, 0, stream>>>(dec_in, wt3, dec_b1, hA, 64);
    gemm_mfma<<<g, 256, 0, stream>>>(hA, wt4, dec_b2, hB, 1024);
    out8_kernel<<<BATCH, 64, 0, stream>>>(hB, dec_w3, dec_b3, nn);

    solver_kernel<<<256, 256, 0, stream>>>(nn, inp, ise, yub, ylb,
                                           P, Pd, Pdd, ws, outf);
}

// Round 6
// 274.538 us; speedup vs baseline: 1.4659x; 1.1388x over previous
//
#include <hip/hip_runtime.h>
#include <hip/hip_bf16.h>
#include <math.h>

// ---------------- problem constants ----------------
#define BATCH   1024
#define NUMPT   100
#define NVAR    11
#define NOBS    10
#define HID     1024
#define INPD    55
#define TRAJD   200

#define T_FIN_C   15.0f
#define K_P_C     20.0f
#define K_D_C     8.944271909999159f   // 2*sqrt(20)
#define K_P_V_C   20.0f
#define A_OBS_C   8.0f
#define B_OBS_C   4.2f
#define RHO_V_C      1.0f
#define RHO_PROJ_C   1.0f
#define RHO_LANE_C   100.0f
#define RHO_OBS_C    100.0f
#define RHO_OFFSET_C 1.0f
#define RHO_INEQ_C   100.0f
#define V_MIN_C   0.1f
#define V_MAX_C   30.0f
#define A_MAX_C   8.0f
#define MAXIT     20

// workspace layout (float offsets)
#define WS_INV1X  0      // 14x14
#define WS_INV1Y  256    // 15x15
#define WS_INV2X  512    // 14x14
#define WS_INV2Y  768    // 15x15
#define WS_SVD    1024   // 4x11 chunk-summed A_vd
#define WS_SPD    1088   // 4x11 chunk-summed A_pd
#define WS_QX     1152   // 11x11
#define WS_QY     1280   // 11x11
#define WS_R2X    1408   // 11x11  inv2x[:11,:11] @ Qx
#define WS_R2Y    1536   // 11x11
#define WS_BIG    2048

typedef __bf16 bf16x8 __attribute__((ext_vector_type(8)));
typedef float  f32x4  __attribute__((ext_vector_type(4)));

// ---------------------------------------------------------------------------
// Precompute: KKT matrices + inverses (GJ w/ partial pivoting — cost1_x's
// 11x11 block is singular), Qx/Qy, R2 = inv2[:11,:11]@Q, chunk-summed
// A_vd/A_pd. grid = 4 blocks, 256 threads.
// ---------------------------------------------------------------------------
__global__ __launch_bounds__(256) void precompute_kernel(
    const float* __restrict__ Pg, const float* __restrict__ Pdg,
    const float* __restrict__ Pddg, float* __restrict__ ws)
{
    __shared__ float sP[NUMPT*NVAR], sPd[NUMPT*NVAR], sPdd[NUMPT*NVAR];
    __shared__ float aug[15][31];
    __shared__ float fcol[15];
    __shared__ float sQ[121];
    __shared__ float s_pivinv;
    __shared__ int   s_pidx;
    const int tid = threadIdx.x, bid = blockIdx.x;

    for (int i = tid; i < NUMPT*NVAR; i += blockDim.x) {
        sP[i] = Pg[i]; sPd[i] = Pdg[i]; sPdd[i] = Pddg[i];
    }
    for (int i = tid; i < 15*31; i += blockDim.x) (&aug[0][0])[i] = 0.0f;
    __syncthreads();

    const int N = (bid == 0 || bid == 2) ? 14 : 15;

    if (tid < 121) {
        const int i = tid / 11, j = tid % 11;
        float s = 0.0f;
        if (bid == 0) {
            for (int t = 0; t < NUMPT; ++t) {
                float pdd_i = sPdd[t*NVAR+i], pdd_j = sPdd[t*NVAR+j];
                float av_i = pdd_i - K_P_V_C * sPd[t*NVAR+i];
                float av_j = pdd_j - K_P_V_C * sPd[t*NVAR+j];
                s += pdd_i*pdd_j + RHO_V_C * av_i*av_j;
            }
        } else if (bid == 1) {
            for (int t = 0; t < NUMPT; ++t) {
                float pdd_i = sPdd[t*NVAR+i], pdd_j = sPdd[t*NVAR+j];
                float ap_i = pdd_i - K_P_C*sP[t*NVAR+i] - K_D_C*sPd[t*NVAR+i];
                float ap_j = pdd_j - K_P_C*sP[t*NVAR+j] - K_D_C*sPd[t*NVAR+j];
                s += pdd_i*pdd_j + RHO_OFFSET_C * ap_i*ap_j;
            }
        } else {
            float obs_w = RHO_OBS_C * (float)NOBS;
            if (bid == 3) obs_w += RHO_LANE_C * 2.0f;
            for (int t = 0; t < NUMPT; ++t) {
                float p_i = sP[t*NVAR+i],   p_j = sP[t*NVAR+j];
                float pd_i = sPd[t*NVAR+i], pd_j = sPd[t*NVAR+j];
                float pdd_i = sPdd[t*NVAR+i], pdd_j = sPdd[t*NVAR+j];
                s += obs_w*p_i*p_j + RHO_INEQ_C*(pdd_i*pdd_j + pd_i*pd_j);
            }
            if (i == j) s += RHO_PROJ_C;
        }
        aug[i][j] = s;
    }
    if (tid < 11) {
        const int i = tid;
        float a0 = sP[i], a1 = sPd[i], a2 = sPdd[i];
        aug[i][11] = a0; aug[11][i] = a0;
        aug[i][12] = a1; aug[12][i] = a1;
        aug[i][13] = a2; aug[13][i] = a2;
        if (N == 15) { float a3 = sPd[99*NVAR + i]; aug[i][14] = a3; aug[14][i] = a3; }
    }
    if (tid < N) aug[tid][N + tid] = 1.0f;

    if (bid == 0 && tid < 44) {
        const int c = tid / 11, k = tid % 11;
        float sv = 0.0f, sp = 0.0f;
        for (int t = 25*c; t < 25*c + 25; ++t) {
            float p = sP[t*NVAR+k], pd = sPd[t*NVAR+k], pdd = sPdd[t*NVAR+k];
            sv += pdd - K_P_V_C * pd;
            sp += pdd - K_P_C * p - K_D_C * pd;
        }
        ws[WS_SVD + tid] = sv;
        ws[WS_SPD + tid] = sp;
    }
    __syncthreads();

    if ((bid == 2 || bid == 3) && tid < 121) {
        float v = aug[tid/11][tid%11];
        if (tid/11 == tid%11) v -= RHO_PROJ_C;
        sQ[tid] = v;
        ws[(bid == 2 ? WS_QX : WS_QY) + tid] = v;
    }

    for (int k = 0; k < N; ++k) {
        if (tid == 0) {
            int p = k; float best = fabsf(aug[k][k]);
            for (int i = k+1; i < N; ++i) {
                float v = fabsf(aug[i][k]);
                if (v > best) { best = v; p = i; }
            }
            s_pidx = p;
        }
        __syncthreads();
        const int p = s_pidx;
        if (p != k && tid < 2*N) {
            float tmp = aug[k][tid]; aug[k][tid] = aug[p][tid]; aug[p][tid] = tmp;
        }
        __syncthreads();
        if (tid == 0) s_pivinv = 1.0f / aug[k][k];
        __syncthreads();
        if (tid < 2*N) aug[k][tid] *= s_pivinv;
        __syncthreads();
        if (tid < N) fcol[tid] = (tid == k) ? 0.0f : aug[tid][k];
        __syncthreads();
        for (int idx = tid; idx < N*2*N; idx += blockDim.x) {
            const int i = idx / (2*N), j = idx % (2*N);
            if (i != k) aug[i][j] = fmaf(-fcol[i], aug[k][j], aug[i][j]);
        }
        __syncthreads();
    }

    float* dst = ws + (bid == 0 ? WS_INV1X : bid == 1 ? WS_INV1Y
                      : bid == 2 ? WS_INV2X : WS_INV2Y);
    for (int idx = tid; idx < N*N; idx += blockDim.x)
        dst[idx] = aug[idx / N][N + idx % N];
    __syncthreads();

    // R2 = inv2[:11,:11] @ Q  (inverse sits in aug[:, N:2N])
    if ((bid == 2 || bid == 3) && tid < 121) {
        const int k = tid / 11, j = tid % 11;
        float a = 0.0f;
        #pragma unroll
        for (int m = 0; m < 11; ++m) a = fmaf(aug[k][N + m], sQ[m*11 + j], a);
        ws[(bid == 2 ? WS_R2X : WS_R2Y) + tid] = a;
    }
}

// ---------------------------------------------------------------------------
// All four weight transposes+bf16 casts in one launch.
// seg0: enc_w1 [255->256]x1024 ; seg1: enc_w2 1024x1024 ;
// seg2: dec_w1 [57->64]x1024   ; seg3: dec_w2 1024x1024.
// ---------------------------------------------------------------------------
__global__ __launch_bounds__(256) void convert_all(
    const float* __restrict__ w1, const float* __restrict__ w2,
    const float* __restrict__ w3, const float* __restrict__ w4,
    __bf16* __restrict__ o1, __bf16* __restrict__ o2,
    __bf16* __restrict__ o3, __bf16* __restrict__ o4)
{
    const int idx = blockIdx.x * 256 + threadIdx.x;
    if (idx < 262144) {
        const int n = idx >> 8, k = idx & 255;
        o1[idx] = (__bf16)((k < 255) ? w1[(size_t)k*HID + n] : 0.0f);
    } else if (idx < 262144 + 1048576) {
        const int i = idx - 262144;
        const int n = i >> 10, k = i & 1023;
        o2[i] = (__bf16)w2[(size_t)k*HID + n];
    } else if (idx < 262144 + 1048576 + 65536) {
        const int i = idx - (262144 + 1048576);
        const int n = i >> 6, k = i & 63;
        o3[i] = (__bf16)((k < 57) ? w3[(size_t)k*HID + n] : 0.0f);
    } else {
        const int i = idx - (262144 + 1048576 + 65536);
        const int n = i >> 10, k = i & 1023;
        o4[i] = (__bf16)w4[(size_t)k*HID + n];
    }
}

// ---------------------------------------------------------------------------
// Input prep -> bf16: enc_in [B][256] = [inp_n(55), traj(200), 0];
// dec_in [B][64] cols 2..56 = inp_n, 57..63 = 0 (cols 0..1 by z_kernel).
// ---------------------------------------------------------------------------
__global__ __launch_bounds__(256) void prep_bf(
    const float* __restrict__ inp, const float* __restrict__ traj,
    const float* __restrict__ mean, const float* __restrict__ stdv,
    __bf16* __restrict__ enc_in, __bf16* __restrict__ dec_in)
{
    __shared__ float sn[INPD];
    const int b = blockIdx.x, t = threadIdx.x;
    if (t < INPD) {
        const float v = (inp[b*INPD + t] - mean[t]) / stdv[t];
        sn[t] = v;
        enc_in[b*256 + t] = (__bf16)v;
    } else if (t < 255) {
        enc_in[b*256 + t] = (__bf16)traj[b*TRAJD + (t - INPD)];
    } else {
        enc_in[b*256 + 255] = (__bf16)0.0f;
    }
    __syncthreads();
    if (t >= 2 && t < 64)
        dec_in[b*64 + t] = (__bf16)((t < 57) ? sn[t - 2] : 0.0f);
}

// ---------------------------------------------------------------------------
// bf16 MFMA GEMM: C = relu(A[1024][Kp] @ Wt^T + bias), Wt [N][Kp].
// 64x64 tile, BK=64, 8 WAVES (512 thr): each wave a 16x32 sub-tile via 2x
// mfma_f32_16x16x32_bf16 per kc. 2 waves/SIMD hides K-loop latency (R5's
// 4-wave version left each SIMD with 1 wave).
// ---------------------------------------------------------------------------
__global__ __launch_bounds__(512) void gemm_mfma(
    const __bf16* __restrict__ A, const __bf16* __restrict__ Wt,
    const float* __restrict__ bias, __bf16* __restrict__ C, int Kp)
{
    __shared__ __bf16 As[64][72];
    __shared__ __bf16 Bs[64][72];
    const int tid = threadIdx.x;
    const int lane = tid & 63, wv = tid >> 6;
    const int wm = (wv >> 1) * 16, wn = (wv & 1) * 32;
    const int ln = lane & 15, q = lane >> 4;
    const int row0 = blockIdx.y * 64, col0 = blockIdx.x * 64;
    const int lrow = tid >> 3, lc = (tid & 7) * 8;

    f32x4 acc0 = (f32x4){0,0,0,0}, acc1 = (f32x4){0,0,0,0};

    for (int k0 = 0; k0 < Kp; k0 += 64) {
        *(bf16x8*)&As[lrow][lc] =
            *(const bf16x8*)&A[(size_t)(row0 + lrow) * Kp + k0 + lc];
        *(bf16x8*)&Bs[lrow][lc] =
            *(const bf16x8*)&Wt[(size_t)(col0 + lrow) * Kp + k0 + lc];
        __syncthreads();
        #pragma unroll
        for (int kc = 0; kc < 2; ++kc) {
            const bf16x8 a  = *(const bf16x8*)&As[wm + ln][kc*32 + q*8];
            const bf16x8 b0 = *(const bf16x8*)&Bs[wn + ln][kc*32 + q*8];
            const bf16x8 b1 = *(const bf16x8*)&Bs[wn + 16 + ln][kc*32 + q*8];
            acc0 = __builtin_amdgcn_mfma_f32_16x16x32_bf16(a, b0, acc0, 0, 0, 0);
            acc1 = __builtin_amdgcn_mfma_f32_16x16x32_bf16(a, b1, acc1, 0, 0, 0);
        }
        __syncthreads();
    }
    // epilogue: D col = lane&15, row = quad*4 + reg  [m89-verified mapping]
    #pragma unroll
    for (int ni = 0; ni < 2; ++ni) {
        const int col = col0 + wn + ni*16 + ln;
        const float bv = bias[col];
        const f32x4 av = ni ? acc1 : acc0;
        #pragma unroll
        for (int r = 0; r < 4; ++r) {
            const int row = row0 + wm + q*4 + r;
            C[(size_t)row * HID + col] = (__bf16)fmaxf(av[r] + bv, 0.0f);
        }
    }
}

// ---------------------------------------------------------------------------
__global__ __launch_bounds__(64) void z_kernel(
    const __bf16* __restrict__ h, const float* __restrict__ wmu,
    const float* __restrict__ bmu, const float* __restrict__ wlv,
    const float* __restrict__ blv, const float* __restrict__ eps,
    __bf16* __restrict__ dec_in)
{
    const int b = blockIdx.x, lane = threadIdx.x;
    float a0 = 0, a1 = 0, a2 = 0, a3 = 0;
    for (int hh = lane; hh < HID; hh += 64) {
        const float v = (float)h[b*HID + hh];
        a0 = fmaf(v, wmu[hh*2 + 0], a0);
        a1 = fmaf(v, wmu[hh*2 + 1], a1);
        a2 = fmaf(v, wlv[hh*2 + 0], a2);
        a3 = fmaf(v, wlv[hh*2 + 1], a3);
    }
    #pragma unroll
    for (int off = 32; off; off >>= 1) {
        a0 += __shfl_down(a0, off);
        a1 += __shfl_down(a1, off);
        a2 += __shfl_down(a2, off);
        a3 += __shfl_down(a3, off);
    }
    if (lane == 0) {
        const float mu0 = a0 + bmu[0], mu1 = a1 + bmu[1];
        const float lv0 = a2 + blv[0], lv1 = a3 + blv[1];
        dec_in[b*64 + 0] = (__bf16)fmaf(expf(0.5f*lv0), eps[b*2 + 0], mu0);
        dec_in[b*64 + 1] = (__bf16)fmaf(expf(0.5f*lv1), eps[b*2 + 1], mu1);
    }
}

// ---------------------------------------------------------------------------
__global__ __launch_bounds__(64) void out8_kernel(
    const __bf16* __restrict__ h, const float* __restrict__ w3,
    const float* __restrict__ b3, float* __restrict__ nn_out)
{
    const int b = blockIdx.x, lane = threadIdx.x;
    float acc[8] = {};
    for (int hh = lane; hh < HID; hh += 64) {
        const float v = (float)h[b*HID + hh];
        #pragma unroll
        for (int j = 0; j < 8; ++j) acc[j] = fmaf(v, w3[hh*8 + j], acc[j]);
    }
    #pragma unroll
    for (int j = 0; j < 8; ++j)
        #pragma unroll
        for (int off = 32; off; off >>= 1) acc[j] += __shfl_down(acc[j], off);
    if (lane == 0)
        for (int j = 0; j < 8; ++j) nn_out[b*8 + j] = acc[j] + b3[j];
}

// ---------------------------------------------------------------------------
// ADMM solver: TWO waves per batch element (128-thr block, grid=1024).
// 4 blocks/CU -> 8 waves/CU (2/SIMD): R5's 1-wave/element design capped at
// 4 waves/CU (1/SIMD) and stalled on dependent-FMA latency (VALUBusy 37%).
//  Phase A: 1 timepoint per lane (lanes 0..99); basis rows + obstacle
//           trajectories register-resident.
//  Phase B: 77 dots split into 154 half-dots over 128 lanes (b128 reads,
//           register basis columns via shared sBcol).
//  Phase C: lanes 0..21 (wave 0), lam/c_bar in registers, R2-folded solve.
// ---------------------------------------------------------------------------
#define DOT11(bb, a0, a1, a2) \
    fmaf(bb[0],a0.x, fmaf(bb[1],a0.y, fmaf(bb[2],a0.z, fmaf(bb[3],a0.w, \
    fmaf(bb[4],a1.x, fmaf(bb[5],a1.y, fmaf(bb[6],a1.z, fmaf(bb[7],a1.w, \
    fmaf(bb[8],a2.x, fmaf(bb[9],a2.y, bb[10]*a2.z))))))))))

__global__ __launch_bounds__(128) void solver_kernel(
    const float* __restrict__ nn_out, const float* __restrict__ inp,
    const float* __restrict__ ise, const float* __restrict__ yub_p,
    const float* __restrict__ ylb_p,
    const float* __restrict__ Pg, const float* __restrict__ Pdg,
    const float* __restrict__ Pddg,
    const float* __restrict__ ws, float* __restrict__ out)
{
    __shared__ __align__(16) float sBcol[3][11][108];   // basis columns, t-pad 0
    __shared__ float s_i2x[196], s_i2y[225], sR2x[121], sR2y[121];
    __shared__ __align__(16) float rows[7][104];        // residual rows, t-pad 0
    __shared__ float dval[2][80];                       // half-dot partials
    __shared__ __align__(16) float cxs[12], cys[12];
    __shared__ float wlin[24];
    __shared__ float obsS[4][10];

    const int tid = threadIdx.x;
    const int e = blockIdx.x;

    // ---- cooperative staging ----
    for (int i = tid; i < 3*11*108; i += 128) {
        const int mat = i / 1188, rem = i - mat*1188;
        const int k = rem / 108, t = rem - k*108;
        const float* G = (mat == 0) ? Pg : (mat == 1 ? Pdg : Pddg);
        sBcol[mat][k][t] = (t < NUMPT) ? G[t*NVAR + k] : 0.0f;
    }
    for (int i = tid; i < 196; i += 128) s_i2x[i] = ws[WS_INV2X + i];
    for (int i = tid; i < 225; i += 128) s_i2y[i] = ws[WS_INV2Y + i];
    for (int i = tid; i < 121; i += 128) { sR2x[i] = ws[WS_R2X + i]; sR2y[i] = ws[WS_R2Y + i]; }
    if (tid < 40) obsS[tid/10][tid%10] = inp[e*INPD + 5 + (tid/10) + 5*(tid%10)];
    if (tid >= 40 && tid < 68) rows[(tid-40) >> 2][100 + ((tid-40) & 3)] = 0.0f;
    if (tid == 68) cxs[11] = 0.0f;
    if (tid == 69) cys[11] = 0.0f;

    // ---- per-lane register preloads ----
    const bool isA = (tid < NUMPT);
    float bP[NVAR], bPd[NVAR], bPdd[NVAR];
    if (isA) {
        #pragma unroll
        for (int k = 0; k < NVAR; ++k) {
            bP[k] = Pg[tid*NVAR+k]; bPd[k] = Pdg[tid*NVAR+k]; bPdd[k] = Pddg[tid*NVAR+k];
        }
    }

    // phase-B half-dot assignment: dot d = r*11+k (r: 0 SX.P, 1 AX.Pdd,
    // 2 VX.Pd, 3 SY.P, 4 AY.Pdd, 5 VY.Pd, 6 LN.P); halves: t 0..51 / 52..103.
    const int d1 = (tid < 77) ? tid : tid - 77;
    const int h1 = (tid < 77) ? 0 : 1;
    const int r1 = d1 / 11, k1 = d1 - 11*r1;
    const int m1 = (r1==1||r1==4) ? 2 : ((r1==2||r1==5) ? 1 : 0);
    const float* colp1 = &sBcol[m1][k1][h1*52];
    const float* rowp1 = &rows[r1][h1*52];
    const bool hasB2 = (tid < 26);
    const int d2 = 51 + tid;                       // valid when hasB2
    const int r2 = d2 / 11, k2 = d2 - 11*r2;
    const int m2 = (r2==1||r2==4) ? 2 : ((r2==2||r2==5) ? 1 : 0);
    const float* colp2 = &sBcol[m2][k2][52];
    const float* rowp2 = &rows[r2][52];

    const float vx0 = ise[e*4 + 2], vy0 = ise[e*4 + 3];
    const float yub = yub_p[e], ylb = ylb_p[e];
    __syncthreads();

    // obstacle trajectories -> registers (iteration-invariant)
    const float DT = T_FIN_C / 99.0f;
    float xo[NOBS], yo[NOBS];
    if (isA) {
        #pragma unroll
        for (int o = 0; o < NOBS; ++o) {
            xo[o] = fmaf(obsS[2][o], tid*DT, obsS[0][o]);
            yo[o] = fmaf(obsS[3][o], tid*DT, obsS[1][o]);
        }
    }

    // ---- lincost broadcast + c_bar init ----
    if (tid < 11) {
        float s = 0;
        #pragma unroll
        for (int c = 0; c < 4; ++c)
            s = fmaf(nn_out[e*8 + c], ws[WS_SVD + c*11 + tid], s);
        wlin[tid] = RHO_V_C * K_P_V_C * s;
    } else if (tid < 22) {
        const int k = tid - 11;
        float s = 0;
        #pragma unroll
        for (int c = 0; c < 4; ++c)
            s = fmaf(nn_out[e*8 + 4 + c], ws[WS_SPD + c*11 + k], s);
        wlin[tid] = RHO_OFFSET_C * K_P_C * s;
    }
    __syncthreads();

    float lam = 0.0f, cb = 0.0f;
    if (tid < 11) {
        const int k = tid;
        float a = vx0 * ws[WS_INV1X + k*14 + 12];
        #pragma unroll
        for (int j = 0; j < NVAR; ++j)
            a = fmaf(-wlin[j], ws[WS_INV1X + k*14 + j], a);
        cb = a; cxs[k] = a;
    } else if (tid < 22) {
        const int k = tid - 11;
        float a = vy0 * ws[WS_INV1Y + k*15 + 12];
        #pragma unroll
        for (int j = 0; j < NVAR; ++j)
            a = fmaf(-wlin[11 + j], ws[WS_INV1Y + k*15 + j], a);
        cb = a; cys[k] = a;
    }
    __syncthreads();

    // ---- main loop ----
    for (int it = 0; it < MAXIT; ++it) {
        // -------- phase A: one timepoint per lane --------
        if (isA) {
            const int t = tid;
            const float4 x0 = *(const float4*)&cxs[0];
            const float4 x1 = *(const float4*)&cxs[4];
            const float4 x2 = *(const float4*)&cxs[8];
            const float4 y0 = *(const float4*)&cys[0];
            const float4 y1 = *(const float4*)&cys[4];
            const float4 y2 = *(const float4*)&cys[8];
            const float px   = DOT11(bP,   x0, x1, x2);
            const float py   = DOT11(bP,   y0, y1, y2);
            const float pxd  = DOT11(bPd,  x0, x1, x2);
            const float pyd  = DOT11(bPd,  y0, y1, y2);
            const float pxdd = DOT11(bPdd, x0, x1, x2);
            const float pydd = DOT11(bPdd, y0, y1, y2);

            float srx = 0.0f, sry = 0.0f;
            #pragma unroll
            for (int o = 0; o < NOBS; ++o) {
                const float wc = px - xo[o], wsv = py - yo[o];
                const float aw = A_OBS_C * wsv, bw = B_OBS_C * wc;
                const float rr2 = aw*aw + bw*bw;
                float ca, sa;
                if (rr2 > 0.0f) { const float ri = rsqrtf(rr2); ca = bw*ri; sa = aw*ri; }
                else            { ca = 1.0f; sa = 0.0f; }
                const float c1 = RHO_OBS_C * (A_OBS_C*A_OBS_C*ca*ca + B_OBS_C*B_OBS_C*sa*sa);
                const float c2 = RHO_OBS_C * (A_OBS_C*wc*ca + B_OBS_C*wsv*sa);
                const float d_o = fmaxf(1.0f, c2 / c1);
                srx += wc - A_OBS_C * d_o * ca;
                sry += wsv - B_OBS_C * d_o * sa;
            }
            float cv, sv, rv;
            const float rv2 = pxd*pxd + pyd*pyd;
            if (rv2 > 0.0f) { const float ri = rsqrtf(rv2); rv = rv2*ri; cv = pxd*ri; sv = pyd*ri; }
            else            { rv = 0.0f; cv = 1.0f; sv = 0.0f; }
            const float dv = fminf(fmaxf(rv, V_MIN_C), V_MAX_C);
            float caa, saa, ra;
            const float ra2 = pxdd*pxdd + pydd*pydd;
            if (ra2 > 0.0f) { const float ri = rsqrtf(ra2); ra = ra2*ri; caa = pxdd*ri; saa = pydd*ri; }
            else            { ra = 0.0f; caa = 1.0f; saa = 0.0f; }
            const float da = fminf(ra, A_MAX_C);

            rows[0][t] = srx;
            rows[1][t] = pxdd - da*caa;
            rows[2][t] = pxd  - dv*cv;
            rows[3][t] = sry;
            rows[4][t] = pydd - da*saa;
            rows[5][t] = pyd  - dv*sv;
            rows[6][t] = fmaxf(0.0f, py - yub) - fmaxf(0.0f, ylb - py);
        }
        __syncthreads();

        // -------- phase B: 154 half-dots over 128 lanes --------
        {
            float s = 0.0f;
            #pragma unroll
            for (int i = 0; i < 13; ++i) {
                const float4 rr = *(const float4*)&rowp1[i*4];
                const float4 cc = *(const float4*)&colp1[i*4];
                s = fmaf(rr.x, cc.x, s); s = fmaf(rr.y, cc.y, s);
                s = fmaf(rr.z, cc.z, s); s = fmaf(rr.w, cc.w, s);
            }
            dval[h1][d1] = s;
            if (hasB2) {
                float s2 = 0.0f;
                #pragma unroll
                for (int i = 0; i < 13; ++i) {
                    const float4 rr = *(const float4*)&rowp2[i*4];
                    const float4 cc = *(const float4*)&colp2[i*4];
                    s2 = fmaf(rr.x, cc.x, s2); s2 = fmaf(rr.y, cc.y, s2);
                    s2 = fmaf(rr.z, cc.z, s2); s2 = fmaf(rr.w, cc.w, s2);
                }
                dval[1][d2] = s2;
            }
        }
        __syncthreads();

        // -------- phase C (wave 0, lanes 0..21) --------
        if (tid < 22) {
            const int k = (tid < 11) ? tid : tid - 11;
            float u;
            if (tid < 11)
                u = RHO_OBS_C * ((dval[0][k]      + dval[1][k])
                               + (dval[0][11 + k] + dval[1][11 + k])
                               + (dval[0][22 + k] + dval[1][22 + k]));
            else
                u = RHO_OBS_C * ((dval[0][33 + k] + dval[1][33 + k])
                               + (dval[0][44 + k] + dval[1][44 + k])
                               + (dval[0][55 + k] + dval[1][55 + k])
                               + (dval[0][66 + k] + dval[1][66 + k]));
            wlin[tid] = 2.0f*u - lam - cb;
            lam -= u;
        }
        __builtin_amdgcn_wave_barrier();
        if (tid < 22) {
            const int k = (tid < 11) ? tid : tid - 11;
            if (tid < 11) {
                float a = vx0 * s_i2x[k*14 + 12];
                #pragma unroll
                for (int j = 0; j < NVAR; ++j) {
                    a = fmaf(-wlin[j], s_i2x[k*14 + j], a);
                    a = fmaf(sR2x[k*11 + j], cxs[j], a);
                }
                cxs[k] = a;
            } else {
                float a = vy0 * s_i2y[k*15 + 12];
                #pragma unroll
                for (int j = 0; j < NVAR; ++j) {
                    a = fmaf(-wlin[11 + j], s_i2y[k*15 + j], a);
                    a = fmaf(sR2y[k*11 + j], cys[j], a);
                }
                cys[k] = a;
            }
        }
        __syncthreads();
    }

    if (tid < NVAR) {
        out[e*22 + tid]      = cxs[tid];
        out[e*22 + 11 + tid] = cys[tid];
    }
}

// ---------------------------------------------------------------------------
extern "C" void kernel_launch(void* const* d_in, const int* in_sizes, int n_in,
                              void* d_out, int out_size, void* d_ws, size_t ws_size,
                              hipStream_t stream)
{
    (void)in_sizes; (void)n_in; (void)out_size; (void)ws_size;
    const float* inp    = (const float*)d_in[0];
    const float* ise    = (const float*)d_in[1];
    const float* traj   = (const float*)d_in[2];
    const float* yub    = (const float*)d_in[3];
    const float* ylb    = (const float*)d_in[4];
    const float* eps    = (const float*)d_in[5];
    const float* enc_w1 = (const float*)d_in[6];
    const float* enc_b1 = (const float*)d_in[7];
    const float* enc_w2 = (const float*)d_in[8];
    const float* enc_b2 = (const float*)d_in[9];
    const float* wmu    = (const float*)d_in[10];
    const float* bmu    = (const float*)d_in[11];
    const float* wlv    = (const float*)d_in[12];
    const float* blv    = (const float*)d_in[13];
    const float* dec_w1 = (const float*)d_in[14];
    const float* dec_b1 = (const float*)d_in[15];
    const float* dec_w2 = (const float*)d_in[16];
    const float* dec_b2 = (const float*)d_in[17];
    const float* dec_w3 = (const float*)d_in[18];
    const float* dec_b3 = (const float*)d_in[19];
    const float* P      = (const float*)d_in[20];
    const float* Pd     = (const float*)d_in[21];
    const float* Pdd    = (const float*)d_in[22];
    const float* mean   = (const float*)d_in[23];
    const float* stdv   = (const float*)d_in[24];

    float* ws   = (float*)d_ws;
    float* nn   = ws + WS_BIG;                        // 1024 x 8 fp32
    __bf16* bfb = (__bf16*)(ws + WS_BIG + BATCH*8);
    __bf16* enc_in = bfb;                             // 1024 x 256
    __bf16* dec_in = enc_in + (size_t)BATCH*256;      // 1024 x 64
    __bf16* hA     = dec_in + (size_t)BATCH*64;       // 1024 x 1024
    __bf16* hB     = hA + (size_t)BATCH*HID;          // 1024 x 1024
    __bf16* wt1    = hB + (size_t)BATCH*HID;          // 1024 x 256
    __bf16* wt2    = wt1 + (size_t)HID*256;           // 1024 x 1024
    __bf16* wt3    = wt2 + (size_t)HID*HID;           // 1024 x 64
    __bf16* wt4    = wt3 + (size_t)HID*64;            // 1024 x 1024
    float* outf = (float*)d_out;

    precompute_kernel<<<4, 256, 0, stream>>>(P, Pd, Pdd, ws);
    convert_all<<<9472, 256, 0, stream>>>(enc_w1, enc_w2, dec_w1, dec_w2,
                                          wt1, wt2, wt3, wt4);
    prep_bf<<<BATCH, 256, 0, stream>>>(inp, traj, mean, stdv, enc_in, dec_in);

    dim3 g(16, 16);
    gemm_mfma<<<g, 512, 0, stream>>>(enc_in, wt1, enc_b1, hA, 256);
    gemm_mfma<<<g, 512, 0, stream>>>(hA, wt2, enc_b2, hB, 1024);
    z_kernel<<<BATCH, 64, 0, stream>>>(hB, wmu, bmu, wlv, blv, eps, dec_in);
    gemm_mfma<<<g, 512, 0, stream>>>(dec_in, wt3, dec_b1, hA, 64);
    gemm_mfma<<<g, 512, 0, stream>>>(hA, wt4, dec_b2, hB, 1024);
    out8_kernel<<<BATCH, 64, 0, stream>>>(hB, dec_w3, dec_b3, nn);

    solver_kernel<<<BATCH, 128, 0, stream>>>(nn, inp, ise, yub, ylb,
                                             P, Pd, Pdd, ws, outf);
}

// Round 7
// 264.301 us; speedup vs baseline: 1.5227x; 1.0387x over previous
//
#include <hip/hip_runtime.h>
#include <hip/hip_bf16.h>
#include <math.h>

// ---------------- problem constants ----------------
#define BATCH   1024
#define NUMPT   100
#define NVAR    11
#define NOBS    10
#define HID     1024
#define INPD    55
#define TRAJD   200

#define T_FIN_C   15.0f
#define K_P_C     20.0f
#define K_D_C     8.944271909999159f   // 2*sqrt(20)
#define K_P_V_C   20.0f
#define A_OBS_C   8.0f
#define B_OBS_C   4.2f
#define AB_C      33.6f                 // A_OBS*B_OBS
#define ABSQ_C    1128.96f              // (A_OBS*B_OBS)^2
#define RHO_V_C      1.0f
#define RHO_PROJ_C   1.0f
#define RHO_LANE_C   100.0f
#define RHO_OBS_C    100.0f
#define RHO_OFFSET_C 1.0f
#define RHO_INEQ_C   100.0f
#define V_MIN_C   0.1f
#define V_MAX_C   30.0f
#define A_MAX_C   8.0f
#define MAXIT     20

// workspace layout (float offsets)
#define WS_INV1X  0      // 14x14
#define WS_INV1Y  256    // 15x15
#define WS_INV2X  512    // 14x14
#define WS_INV2Y  768    // 15x15
#define WS_SVD    1024   // 4x11 chunk-summed A_vd
#define WS_SPD    1088   // 4x11 chunk-summed A_pd
#define WS_QX     1152   // 11x11
#define WS_QY     1280   // 11x11
#define WS_R2X    1408   // 11x11  inv2x[:11,:11] @ Qx
#define WS_R2Y    1536   // 11x11
#define WS_BIG    2048

typedef __bf16 bf16x8 __attribute__((ext_vector_type(8)));
typedef float  f32x4  __attribute__((ext_vector_type(4)));

// ---------------------------------------------------------------------------
// Fused setup kernel (grid 4 + 1024 + 9472 blocks):
//  bid 0..3     : KKT build + GJ inverse (partial pivoting; cost1_x's 11x11
//                 block is singular), Qx/Qy, R2 = inv2@Q, chunk sums.
//  bid 4..1027  : input prep -> bf16 enc_in/dec_in.
//  bid 1028..   : 4 weight transposes + bf16 casts.
// The serial GJ (4 blocks) overlaps with the 13 MB convert instead of
// serializing ahead of the whole pipeline.
// ---------------------------------------------------------------------------
__global__ __launch_bounds__(256) void setup_kernel(
    const float* __restrict__ Pg, const float* __restrict__ Pdg,
    const float* __restrict__ Pddg, float* __restrict__ ws,
    const float* __restrict__ inp, const float* __restrict__ traj,
    const float* __restrict__ mean, const float* __restrict__ stdv,
    __bf16* __restrict__ enc_in, __bf16* __restrict__ dec_in,
    const float* __restrict__ w1, const float* __restrict__ w2,
    const float* __restrict__ w3, const float* __restrict__ w4,
    __bf16* __restrict__ o1, __bf16* __restrict__ o2,
    __bf16* __restrict__ o3, __bf16* __restrict__ o4)
{
    __shared__ float sP[NUMPT*NVAR], sPd[NUMPT*NVAR], sPdd[NUMPT*NVAR];
    __shared__ float aug[15][31];
    __shared__ float fcol[15];
    __shared__ float sQ[121];
    __shared__ float sn[INPD];
    __shared__ float s_pivinv;
    __shared__ int   s_pidx;
    const int tid = threadIdx.x, bid = blockIdx.x;

    if (bid >= 1028) {   // ---------------- weight convert ----------------
        const int idx = (bid - 1028) * 256 + tid;
        if (idx < 262144) {
            const int n = idx >> 8, k = idx & 255;
            o1[idx] = (__bf16)((k < 255) ? w1[(size_t)k*HID + n] : 0.0f);
        } else if (idx < 262144 + 1048576) {
            const int i = idx - 262144;
            const int n = i >> 10, k = i & 1023;
            o2[i] = (__bf16)w2[(size_t)k*HID + n];
        } else if (idx < 262144 + 1048576 + 65536) {
            const int i = idx - (262144 + 1048576);
            const int n = i >> 6, k = i & 63;
            o3[i] = (__bf16)((k < 57) ? w3[(size_t)k*HID + n] : 0.0f);
        } else {
            const int i = idx - (262144 + 1048576 + 65536);
            const int n = i >> 10, k = i & 1023;
            o4[i] = (__bf16)w4[(size_t)k*HID + n];
        }
        return;
    }

    if (bid >= 4) {      // ---------------- input prep ----------------
        const int b = bid - 4;
        if (tid < INPD) {
            const float v = (inp[b*INPD + tid] - mean[tid]) / stdv[tid];
            sn[tid] = v;
            enc_in[b*256 + tid] = (__bf16)v;
        } else if (tid < 255) {
            enc_in[b*256 + tid] = (__bf16)traj[b*TRAJD + (tid - INPD)];
        } else {
            enc_in[b*256 + 255] = (__bf16)0.0f;
        }
        __syncthreads();
        if (tid >= 2 && tid < 64)
            dec_in[b*64 + tid] = (__bf16)((tid < 57) ? sn[tid - 2] : 0.0f);
        return;
    }

    // ---------------- precompute (bid 0..3) ----------------
    for (int i = tid; i < NUMPT*NVAR; i += 256) {
        sP[i] = Pg[i]; sPd[i] = Pdg[i]; sPdd[i] = Pddg[i];
    }
    for (int i = tid; i < 15*31; i += 256) (&aug[0][0])[i] = 0.0f;
    __syncthreads();

    const int N = (bid == 0 || bid == 2) ? 14 : 15;

    if (tid < 121) {
        const int i = tid / 11, j = tid % 11;
        float s = 0.0f;
        if (bid == 0) {
            for (int t = 0; t < NUMPT; ++t) {
                float pdd_i = sPdd[t*NVAR+i], pdd_j = sPdd[t*NVAR+j];
                float av_i = pdd_i - K_P_V_C * sPd[t*NVAR+i];
                float av_j = pdd_j - K_P_V_C * sPd[t*NVAR+j];
                s += pdd_i*pdd_j + RHO_V_C * av_i*av_j;
            }
        } else if (bid == 1) {
            for (int t = 0; t < NUMPT; ++t) {
                float pdd_i = sPdd[t*NVAR+i], pdd_j = sPdd[t*NVAR+j];
                float ap_i = pdd_i - K_P_C*sP[t*NVAR+i] - K_D_C*sPd[t*NVAR+i];
                float ap_j = pdd_j - K_P_C*sP[t*NVAR+j] - K_D_C*sPd[t*NVAR+j];
                s += pdd_i*pdd_j + RHO_OFFSET_C * ap_i*ap_j;
            }
        } else {
            float obs_w = RHO_OBS_C * (float)NOBS;
            if (bid == 3) obs_w += RHO_LANE_C * 2.0f;
            for (int t = 0; t < NUMPT; ++t) {
                float p_i = sP[t*NVAR+i],   p_j = sP[t*NVAR+j];
                float pd_i = sPd[t*NVAR+i], pd_j = sPd[t*NVAR+j];
                float pdd_i = sPdd[t*NVAR+i], pdd_j = sPdd[t*NVAR+j];
                s += obs_w*p_i*p_j + RHO_INEQ_C*(pdd_i*pdd_j + pd_i*pd_j);
            }
            if (i == j) s += RHO_PROJ_C;
        }
        aug[i][j] = s;
    }
    if (tid < 11) {
        const int i = tid;
        float a0 = sP[i], a1 = sPd[i], a2 = sPdd[i];
        aug[i][11] = a0; aug[11][i] = a0;
        aug[i][12] = a1; aug[12][i] = a1;
        aug[i][13] = a2; aug[13][i] = a2;
        if (N == 15) { float a3 = sPd[99*NVAR + i]; aug[i][14] = a3; aug[14][i] = a3; }
    }
    if (tid < N) aug[tid][N + tid] = 1.0f;

    if (bid == 0 && tid < 44) {
        const int c = tid / 11, k = tid % 11;
        float sv = 0.0f, sp = 0.0f;
        for (int t = 25*c; t < 25*c + 25; ++t) {
            float p = sP[t*NVAR+k], pd = sPd[t*NVAR+k], pdd = sPdd[t*NVAR+k];
            sv += pdd - K_P_V_C * pd;
            sp += pdd - K_P_C * p - K_D_C * pd;
        }
        ws[WS_SVD + tid] = sv;
        ws[WS_SPD + tid] = sp;
    }
    __syncthreads();

    if ((bid == 2 || bid == 3) && tid < 121) {
        float v = aug[tid/11][tid%11];
        if (tid/11 == tid%11) v -= RHO_PROJ_C;
        sQ[tid] = v;
        ws[(bid == 2 ? WS_QX : WS_QY) + tid] = v;
    }

    for (int k = 0; k < N; ++k) {
        if (tid == 0) {
            int p = k; float best = fabsf(aug[k][k]);
            for (int i = k+1; i < N; ++i) {
                float v = fabsf(aug[i][k]);
                if (v > best) { best = v; p = i; }
            }
            s_pidx = p;
        }
        __syncthreads();
        const int p = s_pidx;
        if (p != k && tid < 2*N) {
            float tmp = aug[k][tid]; aug[k][tid] = aug[p][tid]; aug[p][tid] = tmp;
        }
        __syncthreads();
        if (tid == 0) s_pivinv = 1.0f / aug[k][k];
        __syncthreads();
        if (tid < 2*N) aug[k][tid] *= s_pivinv;
        __syncthreads();
        if (tid < N) fcol[tid] = (tid == k) ? 0.0f : aug[tid][k];
        __syncthreads();
        for (int idx = tid; idx < N*2*N; idx += 256) {
            const int i = idx / (2*N), j = idx % (2*N);
            if (i != k) aug[i][j] = fmaf(-fcol[i], aug[k][j], aug[i][j]);
        }
        __syncthreads();
    }

    float* dst = ws + (bid == 0 ? WS_INV1X : bid == 1 ? WS_INV1Y
                      : bid == 2 ? WS_INV2X : WS_INV2Y);
    for (int idx = tid; idx < N*N; idx += 256)
        dst[idx] = aug[idx / N][N + idx % N];
    __syncthreads();

    if ((bid == 2 || bid == 3) && tid < 121) {
        const int k = tid / 11, j = tid % 11;
        float a = 0.0f;
        #pragma unroll
        for (int m = 0; m < 11; ++m) a = fmaf(aug[k][N + m], sQ[m*11 + j], a);
        ws[(bid == 2 ? WS_R2X : WS_R2Y) + tid] = a;
    }
}

// ---------------------------------------------------------------------------
// bf16 MFMA GEMM: C = relu(A[1024][Kp] @ Wt^T + bias), Wt [N][Kp].
// 64x64 tile, BK=64, 8 waves (512 thr), each wave 16x32 sub-tile.
// ---------------------------------------------------------------------------
__global__ __launch_bounds__(512) void gemm_mfma(
    const __bf16* __restrict__ A, const __bf16* __restrict__ Wt,
    const float* __restrict__ bias, __bf16* __restrict__ C, int Kp)
{
    __shared__ __bf16 As[64][72];
    __shared__ __bf16 Bs[64][72];
    const int tid = threadIdx.x;
    const int lane = tid & 63, wv = tid >> 6;
    const int wm = (wv >> 1) * 16, wn = (wv & 1) * 32;
    const int ln = lane & 15, q = lane >> 4;
    const int row0 = blockIdx.y * 64, col0 = blockIdx.x * 64;
    const int lrow = tid >> 3, lc = (tid & 7) * 8;

    f32x4 acc0 = (f32x4){0,0,0,0}, acc1 = (f32x4){0,0,0,0};

    for (int k0 = 0; k0 < Kp; k0 += 64) {
        *(bf16x8*)&As[lrow][lc] =
            *(const bf16x8*)&A[(size_t)(row0 + lrow) * Kp + k0 + lc];
        *(bf16x8*)&Bs[lrow][lc] =
            *(const bf16x8*)&Wt[(size_t)(col0 + lrow) * Kp + k0 + lc];
        __syncthreads();
        #pragma unroll
        for (int kc = 0; kc < 2; ++kc) {
            const bf16x8 a  = *(const bf16x8*)&As[wm + ln][kc*32 + q*8];
            const bf16x8 b0 = *(const bf16x8*)&Bs[wn + ln][kc*32 + q*8];
            const bf16x8 b1 = *(const bf16x8*)&Bs[wn + 16 + ln][kc*32 + q*8];
            acc0 = __builtin_amdgcn_mfma_f32_16x16x32_bf16(a, b0, acc0, 0, 0, 0);
            acc1 = __builtin_amdgcn_mfma_f32_16x16x32_bf16(a, b1, acc1, 0, 0, 0);
        }
        __syncthreads();
    }
    #pragma unroll
    for (int ni = 0; ni < 2; ++ni) {
        const int col = col0 + wn + ni*16 + ln;
        const float bv = bias[col];
        const f32x4 av = ni ? acc1 : acc0;
        #pragma unroll
        for (int r = 0; r < 4; ++r) {
            const int row = row0 + wm + q*4 + r;
            C[(size_t)row * HID + col] = (__bf16)fmaxf(av[r] + bv, 0.0f);
        }
    }
}

// ---------------------------------------------------------------------------
__global__ __launch_bounds__(64) void z_kernel(
    const __bf16* __restrict__ h, const float* __restrict__ wmu,
    const float* __restrict__ bmu, const float* __restrict__ wlv,
    const float* __restrict__ blv, const float* __restrict__ eps,
    __bf16* __restrict__ dec_in)
{
    const int b = blockIdx.x, lane = threadIdx.x;
    float a0 = 0, a1 = 0, a2 = 0, a3 = 0;
    for (int hh = lane; hh < HID; hh += 64) {
        const float v = (float)h[b*HID + hh];
        a0 = fmaf(v, wmu[hh*2 + 0], a0);
        a1 = fmaf(v, wmu[hh*2 + 1], a1);
        a2 = fmaf(v, wlv[hh*2 + 0], a2);
        a3 = fmaf(v, wlv[hh*2 + 1], a3);
    }
    #pragma unroll
    for (int off = 32; off; off >>= 1) {
        a0 += __shfl_down(a0, off);
        a1 += __shfl_down(a1, off);
        a2 += __shfl_down(a2, off);
        a3 += __shfl_down(a3, off);
    }
    if (lane == 0) {
        const float mu0 = a0 + bmu[0], mu1 = a1 + bmu[1];
        const float lv0 = a2 + blv[0], lv1 = a3 + blv[1];
        dec_in[b*64 + 0] = (__bf16)fmaf(expf(0.5f*lv0), eps[b*2 + 0], mu0);
        dec_in[b*64 + 1] = (__bf16)fmaf(expf(0.5f*lv1), eps[b*2 + 1], mu1);
    }
}

// ---------------------------------------------------------------------------
__global__ __launch_bounds__(64) void out8_kernel(
    const __bf16* __restrict__ h, const float* __restrict__ w3,
    const float* __restrict__ b3, float* __restrict__ nn_out)
{
    const int b = blockIdx.x, lane = threadIdx.x;
    float acc[8] = {};
    for (int hh = lane; hh < HID; hh += 64) {
        const float v = (float)h[b*HID + hh];
        #pragma unroll
        for (int j = 0; j < 8; ++j) acc[j] = fmaf(v, w3[hh*8 + j], acc[j]);
    }
    #pragma unroll
    for (int j = 0; j < 8; ++j)
        #pragma unroll
        for (int off = 32; off; off >>= 1) acc[j] += __shfl_down(acc[j], off);
    if (lane == 0)
        for (int j = 0; j < 8; ++j) nn_out[b*8 + j] = acc[j] + b3[j];
}

// ---------------------------------------------------------------------------
// ADMM solver: FOUR waves per element (256 thr, grid 1024 -> 16 waves/CU;
// R6's 8 waves/CU still stalled on dependent-FMA latency).
//  Phase A (200 lanes): 2 lanes/timepoint (5 obstacles each -> 9 residual
//    rows SX0,SX1,AX,VX,SY0,SY1,AY,VY,LN). Obstacle math collapsed:
//    d_o = max(1, sqrt(r2)/(A*B)) exactly, so residual = (wc,ws)*f with
//    f = r2<(AB)^2 ? 1-AB*rsqrt(r2) : 0 (no divide). Same for vel/acc.
//  Phase B (198 lanes): 99 dots x 2 halves, b128 LDS reads.
//  Phase C (22 lanes, wave 0): lam/c_bar in regs, R2-folded KKT solve.
// ---------------------------------------------------------------------------
#define DOT11(bb, a0, a1, a2) \
    fmaf(bb[0],a0.x, fmaf(bb[1],a0.y, fmaf(bb[2],a0.z, fmaf(bb[3],a0.w, \
    fmaf(bb[4],a1.x, fmaf(bb[5],a1.y, fmaf(bb[6],a1.z, fmaf(bb[7],a1.w, \
    fmaf(bb[8],a2.x, fmaf(bb[9],a2.y, bb[10]*a2.z))))))))))

__global__ __launch_bounds__(256) void solver_kernel(
    const float* __restrict__ nn_out, const float* __restrict__ inp,
    const float* __restrict__ ise, const float* __restrict__ yub_p,
    const float* __restrict__ ylb_p,
    const float* __restrict__ Pg, const float* __restrict__ Pdg,
    const float* __restrict__ Pddg,
    const float* __restrict__ ws, float* __restrict__ out)
{
    __shared__ __align__(16) float sBcol[3][11][108];   // basis columns, t-pad 0
    __shared__ float s_i2x[196], s_i2y[225], sR2x[121], sR2y[121];
    __shared__ __align__(16) float rows[9][104];        // residual rows, t-pad 0
    __shared__ float dval[2][100];                      // half-dot partials
    __shared__ __align__(16) float cxs[12], cys[12];
    __shared__ float wlin[24];
    __shared__ float obsS[4][10];

    const int tid = threadIdx.x;
    const int e = blockIdx.x;

    // ---- cooperative staging ----
    for (int i = tid; i < 3*11*108; i += 256) {
        const int mat = i / 1188, rem = i - mat*1188;
        const int k = rem / 108, t = rem - k*108;
        const float* G = (mat == 0) ? Pg : (mat == 1 ? Pdg : Pddg);
        sBcol[mat][k][t] = (t < NUMPT) ? G[t*NVAR + k] : 0.0f;
    }
    for (int i = tid; i < 196; i += 256) s_i2x[i] = ws[WS_INV2X + i];
    for (int i = tid; i < 225; i += 256) s_i2y[i] = ws[WS_INV2Y + i];
    for (int i = tid; i < 121; i += 256) { sR2x[i] = ws[WS_R2X + i]; sR2y[i] = ws[WS_R2Y + i]; }
    if (tid >= 200 && tid < 240) {
        const int i = tid - 200;
        obsS[i/10][i%10] = inp[e*INPD + 5 + (i/10) + 5*(i%10)];
    }
    if (tid >= 64 && tid < 100) {       // zero 9 rows x 4 tail pads
        const int i = tid - 64;
        rows[i >> 2][100 + (i & 3)] = 0.0f;
    }
    if (tid == 100) cxs[11] = 0.0f;
    if (tid == 101) cys[11] = 0.0f;

    // ---- roles ----
    const bool isA = (tid < 200);
    const int tA = tid >> 1, hA = tid & 1;      // timepoint, obstacle-half
    const bool isB = (tid < 198);
    const int hB = (tid >= 99) ? 1 : 0;
    const int dB = tid - 99*hB;
    const int rB = dB / 11, kB = dB - 11*rB;
    const int mB = (rB==2||rB==6) ? 2 : ((rB==3||rB==7) ? 1 : 0);
    const float* colp = &sBcol[mB][kB][hB*52];
    const float* rowp = &rows[rB][hB*52];

    float bP[NVAR], bPd[NVAR], bPdd[NVAR];
    if (isA) {
        #pragma unroll
        for (int k = 0; k < NVAR; ++k) bP[k] = Pg[tA*NVAR+k];
        if (hA == 0) {
            #pragma unroll
            for (int k = 0; k < NVAR; ++k) {
                bPd[k] = Pdg[tA*NVAR+k]; bPdd[k] = Pddg[tA*NVAR+k];
            }
        }
    }

    const float vx0 = ise[e*4 + 2], vy0 = ise[e*4 + 3];
    const float yub = yub_p[e], ylb = ylb_p[e];
    __syncthreads();

    // obstacle positions at own timepoint -> registers (5 per lane)
    const float DT = T_FIN_C / 99.0f;
    float xo[5], yo[5];
    if (isA) {
        const int ob0 = 5*hA;
        #pragma unroll
        for (int o = 0; o < 5; ++o) {
            xo[o] = fmaf(obsS[2][ob0+o], tA*DT, obsS[0][ob0+o]);
            yo[o] = fmaf(obsS[3][ob0+o], tA*DT, obsS[1][ob0+o]);
        }
    }

    // ---- lincost broadcast + c_bar init ----
    if (tid < 11) {
        float s = 0;
        #pragma unroll
        for (int c = 0; c < 4; ++c)
            s = fmaf(nn_out[e*8 + c], ws[WS_SVD + c*11 + tid], s);
        wlin[tid] = RHO_V_C * K_P_V_C * s;
    } else if (tid < 22) {
        const int k = tid - 11;
        float s = 0;
        #pragma unroll
        for (int c = 0; c < 4; ++c)
            s = fmaf(nn_out[e*8 + 4 + c], ws[WS_SPD + c*11 + k], s);
        wlin[tid] = RHO_OFFSET_C * K_P_C * s;
    }
    __syncthreads();

    float lam = 0.0f, cb = 0.0f;
    if (tid < 11) {
        const int k = tid;
        float a = vx0 * ws[WS_INV1X + k*14 + 12];
        #pragma unroll
        for (int j = 0; j < NVAR; ++j)
            a = fmaf(-wlin[j], ws[WS_INV1X + k*14 + j], a);
        cb = a; cxs[k] = a;
    } else if (tid < 22) {
        const int k = tid - 11;
        float a = vy0 * ws[WS_INV1Y + k*15 + 12];
        #pragma unroll
        for (int j = 0; j < NVAR; ++j)
            a = fmaf(-wlin[11 + j], ws[WS_INV1Y + k*15 + j], a);
        cb = a; cys[k] = a;
    }
    __syncthreads();

    // ---- main loop ----
    for (int it = 0; it < MAXIT; ++it) {
        // -------- phase A --------
        if (isA) {
            const float4 x0 = *(const float4*)&cxs[0];
            const float4 x1 = *(const float4*)&cxs[4];
            const float4 x2 = *(const float4*)&cxs[8];
            const float4 y0 = *(const float4*)&cys[0];
            const float4 y1 = *(const float4*)&cys[4];
            const float4 y2 = *(const float4*)&cys[8];
            const float px = DOT11(bP, x0, x1, x2);
            const float py = DOT11(bP, y0, y1, y2);

            // obstacles (5 per lane), collapsed repulsion form
            float srx = 0.0f, sry = 0.0f;
            #pragma unroll
            for (int o = 0; o < 5; ++o) {
                const float wc = px - xo[o], wsv = py - yo[o];
                const float aw = A_OBS_C * wsv, bw = B_OBS_C * wc;
                const float r2 = aw*aw + bw*bw;
                if (r2 > 0.0f) {
                    const float f = (r2 < ABSQ_C) ? (1.0f - AB_C * rsqrtf(r2)) : 0.0f;
                    srx = fmaf(wc, f, srx);
                    sry = fmaf(wsv, f, sry);
                } else {
                    srx -= A_OBS_C;
                }
            }
            rows[hA ? 1 : 0][tA] = srx;
            rows[hA ? 5 : 4][tA] = sry;

            if (hA == 0) {
                const float pxd  = DOT11(bPd,  x0, x1, x2);
                const float pyd  = DOT11(bPd,  y0, y1, y2);
                const float pxdd = DOT11(bPdd, x0, x1, x2);
                const float pydd = DOT11(bPdd, y0, y1, y2);
                // velocity projection residual = p*(1 - dv*ri)
                const float rv2 = pxd*pxd + pyd*pyd;
                float vxr, vyr;
                if (rv2 > 0.0f) {
                    const float ri = rsqrtf(rv2);
                    const float dv = fminf(fmaxf(rv2*ri, V_MIN_C), V_MAX_C);
                    const float f = 1.0f - dv*ri;
                    vxr = pxd*f; vyr = pyd*f;
                } else { vxr = -V_MIN_C; vyr = 0.0f; }
                rows[3][tA] = vxr;  rows[7][tA] = vyr;
                // acceleration projection
                const float ra2 = pxdd*pxdd + pydd*pydd;
                float axr = 0.0f, ayr = 0.0f;
                if (ra2 > ABSQ_C*0.0f + A_MAX_C*A_MAX_C) {   // ra > A_MAX
                    const float ri = rsqrtf(ra2);
                    const float f = 1.0f - A_MAX_C*ri;
                    axr = pxdd*f; ayr = pydd*f;
                }
                rows[2][tA] = axr;  rows[6][tA] = ayr;
                // lane residual
                rows[8][tA] = fmaxf(0.0f, py - yub) - fmaxf(0.0f, ylb - py);
            }
        }
        __syncthreads();

        // -------- phase B: 198 half-dots --------
        if (isB) {
            float s = 0.0f;
            #pragma unroll
            for (int i = 0; i < 13; ++i) {
                const float4 rr = *(const float4*)&rowp[i*4];
                const float4 cc = *(const float4*)&colp[i*4];
                s = fmaf(rr.x, cc.x, s); s = fmaf(rr.y, cc.y, s);
                s = fmaf(rr.z, cc.z, s); s = fmaf(rr.w, cc.w, s);
            }
            dval[hB][dB] = s;
        }
        __syncthreads();

        // -------- phase C (wave 0, lanes 0..21) --------
        if (tid < 22) {
            const int k = (tid < 11) ? tid : tid - 11;
            float u;
            if (tid < 11)   // rows 0..3: SX0,SX1,AX,VX
                u = RHO_OBS_C * ((dval[0][k]      + dval[1][k])
                               + (dval[0][11 + k] + dval[1][11 + k])
                               + (dval[0][22 + k] + dval[1][22 + k])
                               + (dval[0][33 + k] + dval[1][33 + k]));
            else            // rows 4..8: SY0,SY1,AY,VY,LN
                u = RHO_OBS_C * ((dval[0][44 + k] + dval[1][44 + k])
                               + (dval[0][55 + k] + dval[1][55 + k])
                               + (dval[0][66 + k] + dval[1][66 + k])
                               + (dval[0][77 + k] + dval[1][77 + k])
                               + (dval[0][88 + k] + dval[1][88 + k]));
            wlin[tid] = 2.0f*u - lam - cb;
            lam -= u;
        }
        __builtin_amdgcn_wave_barrier();
        if (tid < 22) {
            const int k = (tid < 11) ? tid : tid - 11;
            if (tid < 11) {
                float a = vx0 * s_i2x[k*14 + 12];
                #pragma unroll
                for (int j = 0; j < NVAR; ++j) {
                    a = fmaf(-wlin[j], s_i2x[k*14 + j], a);
                    a = fmaf(sR2x[k*11 + j], cxs[j], a);
                }
                cxs[k] = a;
            } else {
                float a = vy0 * s_i2y[k*15 + 12];
                #pragma unroll
                for (int j = 0; j < NVAR; ++j) {
                    a = fmaf(-wlin[11 + j], s_i2y[k*15 + j], a);
                    a = fmaf(sR2y[k*11 + j], cys[j], a);
                }
                cys[k] = a;
            }
        }
        __syncthreads();
    }

    if (tid < NVAR) {
        out[e*22 + tid]      = cxs[tid];
        out[e*22 + 11 + tid] = cys[tid];
    }
}

// ---------------------------------------------------------------------------
extern "C" void kernel_launch(void* const* d_in, const int* in_sizes, int n_in,
                              void* d_out, int out_size, void* d_ws, size_t ws_size,
                              hipStream_t stream)
{
    (void)in_sizes; (void)n_in; (void)out_size; (void)ws_size;
    const float* inp    = (const float*)d_in[0];
    const float* ise    = (const float*)d_in[1];
    const float* traj   = (const float*)d_in[2];
    const float* yub    = (const float*)d_in[3];
    const float* ylb    = (const float*)d_in[4];
    const float* eps    = (const float*)d_in[5];
    const float* enc_w1 = (const float*)d_in[6];
    const float* enc_b1 = (const float*)d_in[7];
    const float* enc_w2 = (const float*)d_in[8];
    const float* enc_b2 = (const float*)d_in[9];
    const float* wmu    = (const float*)d_in[10];
    const float* bmu    = (const float*)d_in[11];
    const float* wlv    = (const float*)d_in[12];
    const float* blv    = (const float*)d_in[13];
    const float* dec_w1 = (const float*)d_in[14];
    const float* dec_b1 = (const float*)d_in[15];
    const float* dec_w2 = (const float*)d_in[16];
    const float* dec_b2 = (const float*)d_in[17];
    const float* dec_w3 = (const float*)d_in[18];
    const float* dec_b3 = (const float*)d_in[19];
    const float* P      = (const float*)d_in[20];
    const float* Pd     = (const float*)d_in[21];
    const float* Pdd    = (const float*)d_in[22];
    const float* mean   = (const float*)d_in[23];
    const float* stdv   = (const float*)d_in[24];

    float* ws   = (float*)d_ws;
    float* nn   = ws + WS_BIG;                        // 1024 x 8 fp32
    __bf16* bfb = (__bf16*)(ws + WS_BIG + BATCH*8);
    __bf16* enc_in = bfb;                             // 1024 x 256
    __bf16* dec_in = enc_in + (size_t)BATCH*256;      // 1024 x 64
    __bf16* hA     = dec_in + (size_t)BATCH*64;       // 1024 x 1024
    __bf16* hB     = hA + (size_t)BATCH*HID;          // 1024 x 1024
    __bf16* wt1    = hB + (size_t)BATCH*HID;          // 1024 x 256
    __bf16* wt2    = wt1 + (size_t)HID*256;           // 1024 x 1024
    __bf16* wt3    = wt2 + (size_t)HID*HID;           // 1024 x 64
    __bf16* wt4    = wt3 + (size_t)HID*64;            // 1024 x 1024
    float* outf = (float*)d_out;

    setup_kernel<<<4 + 1024 + 9472, 256, 0, stream>>>(
        P, Pd, Pdd, ws, inp, traj, mean, stdv, enc_in, dec_in,
        enc_w1, enc_w2, dec_w1, dec_w2, wt1, wt2, wt3, wt4);

    dim3 g(16, 16);
    gemm_mfma<<<g, 512, 0, stream>>>(enc_in, wt1, enc_b1, hA, 256);
    gemm_mfma<<<g, 512, 0, stream>>>(hA, wt2, enc_b2, hB, 1024);
    z_kernel<<<BATCH, 64, 0, stream>>>(hB, wmu, bmu, wlv, blv, eps, dec_in);
    gemm_mfma<<<g, 512, 0, stream>>>(dec_in, wt3, dec_b1, hA, 64);
    gemm_mfma<<<g, 512, 0, stream>>>(hA, wt4, dec_b2, hB, 1024);
    out8_kernel<<<BATCH, 64, 0, stream>>>(hB, dec_w3, dec_b3, nn);

    solver_kernel<<<BATCH, 256, 0, stream>>>(nn, inp, ise, yub, ylb,
                                             P, Pd, Pdd, ws, outf);
}

// Round 8
// 236.556 us; speedup vs baseline: 1.7013x; 1.1173x over previous
//
#include <hip/hip_runtime.h>
#include <hip/hip_bf16.h>
#include <math.h>

// ---------------- problem constants ----------------
#define BATCH   1024
#define NUMPT   100
#define NVAR    11
#define NOBS    10
#define HID     1024
#define INPD    55
#define TRAJD   200

#define T_FIN_C   15.0f
#define K_P_C     20.0f
#define K_D_C     8.944271909999159f   // 2*sqrt(20)
#define K_P_V_C   20.0f
#define A_OBS_C   8.0f
#define B_OBS_C   4.2f
#define AB_C      33.6f                 // A_OBS*B_OBS
#define ABSQ_C    1128.96f              // (A_OBS*B_OBS)^2
#define RHO_V_C      1.0f
#define RHO_PROJ_C   1.0f
#define RHO_LANE_C   100.0f
#define RHO_OBS_C    100.0f
#define RHO_OFFSET_C 1.0f
#define RHO_INEQ_C   100.0f
#define V_MIN_C   0.1f
#define V_MAX_C   30.0f
#define A_MAX_C   8.0f
#define MAXIT     20

// workspace layout (float offsets)
#define WS_INV1X  0      // 14x14
#define WS_INV1Y  256    // 15x15
#define WS_INV2X  512    // 14x14
#define WS_INV2Y  768    // 15x15
#define WS_SVD    1024   // 4x11 chunk-summed A_vd
#define WS_SPD    1088   // 4x11 chunk-summed A_pd
#define WS_QX     1152   // 11x11
#define WS_QY     1280   // 11x11
#define WS_R2X    1408   // 11x11  inv2x[:11,:11] @ Qx
#define WS_R2Y    1536   // 11x11
#define WS_BIG    2048

typedef __bf16 bf16x8 __attribute__((ext_vector_type(8)));
typedef float  f32x4  __attribute__((ext_vector_type(4)));

// ---------------------------------------------------------------------------
// Fused setup kernel (grid 4 + 1024 + 9472):
//  bid 0..3     : KKT build + GJ inverse (partial pivoting), Qx/Qy, R2, sums.
//  bid 4..1027  : input prep -> bf16 enc_in/dec_in.
//  bid 1028..   : 4 weight transposes + bf16 casts (overlaps the serial GJ).
// ---------------------------------------------------------------------------
__global__ __launch_bounds__(256) void setup_kernel(
    const float* __restrict__ Pg, const float* __restrict__ Pdg,
    const float* __restrict__ Pddg, float* __restrict__ ws,
    const float* __restrict__ inp, const float* __restrict__ traj,
    const float* __restrict__ mean, const float* __restrict__ stdv,
    __bf16* __restrict__ enc_in, __bf16* __restrict__ dec_in,
    const float* __restrict__ w1, const float* __restrict__ w2,
    const float* __restrict__ w3, const float* __restrict__ w4,
    __bf16* __restrict__ o1, __bf16* __restrict__ o2,
    __bf16* __restrict__ o3, __bf16* __restrict__ o4)
{
    __shared__ float sP[NUMPT*NVAR], sPd[NUMPT*NVAR], sPdd[NUMPT*NVAR];
    __shared__ float aug[15][31];
    __shared__ float fcol[15];
    __shared__ float sQ[121];
    __shared__ float sn[INPD];
    __shared__ float s_pivinv;
    __shared__ int   s_pidx;
    const int tid = threadIdx.x, bid = blockIdx.x;

    if (bid >= 1028) {   // ---------------- weight convert ----------------
        const int idx = (bid - 1028) * 256 + tid;
        if (idx < 262144) {
            const int n = idx >> 8, k = idx & 255;
            o1[idx] = (__bf16)((k < 255) ? w1[(size_t)k*HID + n] : 0.0f);
        } else if (idx < 262144 + 1048576) {
            const int i = idx - 262144;
            const int n = i >> 10, k = i & 1023;
            o2[i] = (__bf16)w2[(size_t)k*HID + n];
        } else if (idx < 262144 + 1048576 + 65536) {
            const int i = idx - (262144 + 1048576);
            const int n = i >> 6, k = i & 63;
            o3[i] = (__bf16)((k < 57) ? w3[(size_t)k*HID + n] : 0.0f);
        } else {
            const int i = idx - (262144 + 1048576 + 65536);
            const int n = i >> 10, k = i & 1023;
            o4[i] = (__bf16)w4[(size_t)k*HID + n];
        }
        return;
    }

    if (bid >= 4) {      // ---------------- input prep ----------------
        const int b = bid - 4;
        if (tid < INPD) {
            const float v = (inp[b*INPD + tid] - mean[tid]) / stdv[tid];
            sn[tid] = v;
            enc_in[b*256 + tid] = (__bf16)v;
        } else if (tid < 255) {
            enc_in[b*256 + tid] = (__bf16)traj[b*TRAJD + (tid - INPD)];
        } else {
            enc_in[b*256 + 255] = (__bf16)0.0f;
        }
        __syncthreads();
        if (tid >= 2 && tid < 64)
            dec_in[b*64 + tid] = (__bf16)((tid < 57) ? sn[tid - 2] : 0.0f);
        return;
    }

    // ---------------- precompute (bid 0..3) ----------------
    for (int i = tid; i < NUMPT*NVAR; i += 256) {
        sP[i] = Pg[i]; sPd[i] = Pdg[i]; sPdd[i] = Pddg[i];
    }
    for (int i = tid; i < 15*31; i += 256) (&aug[0][0])[i] = 0.0f;
    __syncthreads();

    const int N = (bid == 0 || bid == 2) ? 14 : 15;

    if (tid < 121) {
        const int i = tid / 11, j = tid % 11;
        float s = 0.0f;
        if (bid == 0) {
            for (int t = 0; t < NUMPT; ++t) {
                float pdd_i = sPdd[t*NVAR+i], pdd_j = sPdd[t*NVAR+j];
                float av_i = pdd_i - K_P_V_C * sPd[t*NVAR+i];
                float av_j = pdd_j - K_P_V_C * sPd[t*NVAR+j];
                s += pdd_i*pdd_j + RHO_V_C * av_i*av_j;
            }
        } else if (bid == 1) {
            for (int t = 0; t < NUMPT; ++t) {
                float pdd_i = sPdd[t*NVAR+i], pdd_j = sPdd[t*NVAR+j];
                float ap_i = pdd_i - K_P_C*sP[t*NVAR+i] - K_D_C*sPd[t*NVAR+i];
                float ap_j = pdd_j - K_P_C*sP[t*NVAR+j] - K_D_C*sPd[t*NVAR+j];
                s += pdd_i*pdd_j + RHO_OFFSET_C * ap_i*ap_j;
            }
        } else {
            float obs_w = RHO_OBS_C * (float)NOBS;
            if (bid == 3) obs_w += RHO_LANE_C * 2.0f;
            for (int t = 0; t < NUMPT; ++t) {
                float p_i = sP[t*NVAR+i],   p_j = sP[t*NVAR+j];
                float pd_i = sPd[t*NVAR+i], pd_j = sPd[t*NVAR+j];
                float pdd_i = sPdd[t*NVAR+i], pdd_j = sPdd[t*NVAR+j];
                s += obs_w*p_i*p_j + RHO_INEQ_C*(pdd_i*pdd_j + pd_i*pd_j);
            }
            if (i == j) s += RHO_PROJ_C;
        }
        aug[i][j] = s;
    }
    if (tid < 11) {
        const int i = tid;
        float a0 = sP[i], a1 = sPd[i], a2 = sPdd[i];
        aug[i][11] = a0; aug[11][i] = a0;
        aug[i][12] = a1; aug[12][i] = a1;
        aug[i][13] = a2; aug[13][i] = a2;
        if (N == 15) { float a3 = sPd[99*NVAR + i]; aug[i][14] = a3; aug[14][i] = a3; }
    }
    if (tid < N) aug[tid][N + tid] = 1.0f;

    if (bid == 0 && tid < 44) {
        const int c = tid / 11, k = tid % 11;
        float sv = 0.0f, sp = 0.0f;
        for (int t = 25*c; t < 25*c + 25; ++t) {
            float p = sP[t*NVAR+k], pd = sPd[t*NVAR+k], pdd = sPdd[t*NVAR+k];
            sv += pdd - K_P_V_C * pd;
            sp += pdd - K_P_C * p - K_D_C * pd;
        }
        ws[WS_SVD + tid] = sv;
        ws[WS_SPD + tid] = sp;
    }
    __syncthreads();

    if ((bid == 2 || bid == 3) && tid < 121) {
        float v = aug[tid/11][tid%11];
        if (tid/11 == tid%11) v -= RHO_PROJ_C;
        sQ[tid] = v;
        ws[(bid == 2 ? WS_QX : WS_QY) + tid] = v;
    }

    for (int k = 0; k < N; ++k) {
        if (tid == 0) {
            int p = k; float best = fabsf(aug[k][k]);
            for (int i = k+1; i < N; ++i) {
                float v = fabsf(aug[i][k]);
                if (v > best) { best = v; p = i; }
            }
            s_pidx = p;
        }
        __syncthreads();
        const int p = s_pidx;
        if (p != k && tid < 2*N) {
            float tmp = aug[k][tid]; aug[k][tid] = aug[p][tid]; aug[p][tid] = tmp;
        }
        __syncthreads();
        if (tid == 0) s_pivinv = 1.0f / aug[k][k];
        __syncthreads();
        if (tid < 2*N) aug[k][tid] *= s_pivinv;
        __syncthreads();
        if (tid < N) fcol[tid] = (tid == k) ? 0.0f : aug[tid][k];
        __syncthreads();
        for (int idx = tid; idx < N*2*N; idx += 256) {
            const int i = idx / (2*N), j = idx % (2*N);
            if (i != k) aug[i][j] = fmaf(-fcol[i], aug[k][j], aug[i][j]);
        }
        __syncthreads();
    }

    float* dst = ws + (bid == 0 ? WS_INV1X : bid == 1 ? WS_INV1Y
                      : bid == 2 ? WS_INV2X : WS_INV2Y);
    for (int idx = tid; idx < N*N; idx += 256)
        dst[idx] = aug[idx / N][N + idx % N];
    __syncthreads();

    if ((bid == 2 || bid == 3) && tid < 121) {
        const int k = tid / 11, j = tid % 11;
        float a = 0.0f;
        #pragma unroll
        for (int m = 0; m < 11; ++m) a = fmaf(aug[k][N + m], sQ[m*11 + j], a);
        ws[(bid == 2 ? WS_R2X : WS_R2Y) + tid] = a;
    }
}

// ---------------------------------------------------------------------------
// bf16 MFMA GEMM: C = relu(A[1024][Kp] @ Wt^T + bias), Wt [N][Kp].
// 32x64 tile, BK=64, 4 waves (256 thr), each wave 16x32 sub-tile.
// Grid (16,32) = 512 blocks -> 2 blocks/CU so K-loop barrier/load stalls
// overlap across blocks (R7's 256-block/64x64 config was 1 block/CU = the
// R2 latency trap for MFMA).
// ---------------------------------------------------------------------------
__global__ __launch_bounds__(256) void gemm_mfma(
    const __bf16* __restrict__ A, const __bf16* __restrict__ Wt,
    const float* __restrict__ bias, __bf16* __restrict__ C, int Kp)
{
    __shared__ __bf16 As[32][72];
    __shared__ __bf16 Bs[64][72];
    const int tid = threadIdx.x;
    const int lane = tid & 63, wv = tid >> 6;
    const int wm = (wv >> 1) * 16, wn = (wv & 1) * 32;
    const int ln = lane & 15, q = lane >> 4;
    const int row0 = blockIdx.y * 32, col0 = blockIdx.x * 64;
    const int srow = tid >> 3, lc = (tid & 7) * 8;

    f32x4 acc0 = (f32x4){0,0,0,0}, acc1 = (f32x4){0,0,0,0};

    for (int k0 = 0; k0 < Kp; k0 += 64) {
        *(bf16x8*)&As[srow][lc] =
            *(const bf16x8*)&A[(size_t)(row0 + srow) * Kp + k0 + lc];
        *(bf16x8*)&Bs[srow][lc] =
            *(const bf16x8*)&Wt[(size_t)(col0 + srow) * Kp + k0 + lc];
        *(bf16x8*)&Bs[srow + 32][lc] =
            *(const bf16x8*)&Wt[(size_t)(col0 + srow + 32) * Kp + k0 + lc];
        __syncthreads();
        #pragma unroll
        for (int kc = 0; kc < 2; ++kc) {
            const bf16x8 a  = *(const bf16x8*)&As[wm + ln][kc*32 + q*8];
            const bf16x8 b0 = *(const bf16x8*)&Bs[wn + ln][kc*32 + q*8];
            const bf16x8 b1 = *(const bf16x8*)&Bs[wn + 16 + ln][kc*32 + q*8];
            acc0 = __builtin_amdgcn_mfma_f32_16x16x32_bf16(a, b0, acc0, 0, 0, 0);
            acc1 = __builtin_amdgcn_mfma_f32_16x16x32_bf16(a, b1, acc1, 0, 0, 0);
        }
        __syncthreads();
    }
    // epilogue: D col = lane&15, row = quad*4 + reg  [m89-verified mapping]
    #pragma unroll
    for (int ni = 0; ni < 2; ++ni) {
        const int col = col0 + wn + ni*16 + ln;
        const float bv = bias[col];
        const f32x4 av = ni ? acc1 : acc0;
        #pragma unroll
        for (int r = 0; r < 4; ++r) {
            const int row = row0 + wm + q*4 + r;
            C[(size_t)row * HID + col] = (__bf16)fmaxf(av[r] + bv, 0.0f);
        }
    }
}

// ---------------------------------------------------------------------------
__global__ __launch_bounds__(64) void z_kernel(
    const __bf16* __restrict__ h, const float* __restrict__ wmu,
    const float* __restrict__ bmu, const float* __restrict__ wlv,
    const float* __restrict__ blv, const float* __restrict__ eps,
    __bf16* __restrict__ dec_in)
{
    const int b = blockIdx.x, lane = threadIdx.x;
    float a0 = 0, a1 = 0, a2 = 0, a3 = 0;
    for (int hh = lane; hh < HID; hh += 64) {
        const float v = (float)h[b*HID + hh];
        a0 = fmaf(v, wmu[hh*2 + 0], a0);
        a1 = fmaf(v, wmu[hh*2 + 1], a1);
        a2 = fmaf(v, wlv[hh*2 + 0], a2);
        a3 = fmaf(v, wlv[hh*2 + 1], a3);
    }
    #pragma unroll
    for (int off = 32; off; off >>= 1) {
        a0 += __shfl_down(a0, off);
        a1 += __shfl_down(a1, off);
        a2 += __shfl_down(a2, off);
        a3 += __shfl_down(a3, off);
    }
    if (lane == 0) {
        const float mu0 = a0 + bmu[0], mu1 = a1 + bmu[1];
        const float lv0 = a2 + blv[0], lv1 = a3 + blv[1];
        dec_in[b*64 + 0] = (__bf16)fmaf(expf(0.5f*lv0), eps[b*2 + 0], mu0);
        dec_in[b*64 + 1] = (__bf16)fmaf(expf(0.5f*lv1), eps[b*2 + 1], mu1);
    }
}

// ---------------------------------------------------------------------------
__global__ __launch_bounds__(64) void out8_kernel(
    const __bf16* __restrict__ h, const float* __restrict__ w3,
    const float* __restrict__ b3, float* __restrict__ nn_out)
{
    const int b = blockIdx.x, lane = threadIdx.x;
    float acc[8] = {};
    for (int hh = lane; hh < HID; hh += 64) {
        const float v = (float)h[b*HID + hh];
        #pragma unroll
        for (int j = 0; j < 8; ++j) acc[j] = fmaf(v, w3[hh*8 + j], acc[j]);
    }
    #pragma unroll
    for (int j = 0; j < 8; ++j)
        #pragma unroll
        for (int off = 32; off; off >>= 1) acc[j] += __shfl_down(acc[j], off);
    if (lane == 0)
        for (int j = 0; j < 8; ++j) nn_out[b*8 + j] = acc[j] + b3[j];
}

// ---------------------------------------------------------------------------
// ADMM solver, 4 waves/element (grid 1024), work-reduced:
//  Phase A (200 lanes, BALANCED 2-lane/point split):
//    even lane: px,py,pxd,pyd -> vel residuals + lane residual + obs 0..4
//    odd lane:  px,py,pxdd,pydd -> acc residuals + obs 5..9
//    obstacle half-sums merged via __shfl_xor -> 7 residual rows (was 9).
//  Phase B (154 lanes): 77 dots x 2 halves, b128 reads, 2-acc ILP.
//  Phase C (22 lanes, wave 0): lam/c_bar in regs, R2-folded KKT solve.
// ---------------------------------------------------------------------------
#define DOT11(bb, a0, a1, a2) \
    fmaf(bb[0],a0.x, fmaf(bb[1],a0.y, fmaf(bb[2],a0.z, fmaf(bb[3],a0.w, \
    fmaf(bb[4],a1.x, fmaf(bb[5],a1.y, fmaf(bb[6],a1.z, fmaf(bb[7],a1.w, \
    fmaf(bb[8],a2.x, fmaf(bb[9],a2.y, bb[10]*a2.z))))))))))

__global__ __launch_bounds__(256) void solver_kernel(
    const float* __restrict__ nn_out, const float* __restrict__ inp,
    const float* __restrict__ ise, const float* __restrict__ yub_p,
    const float* __restrict__ ylb_p,
    const float* __restrict__ Pg, const float* __restrict__ Pdg,
    const float* __restrict__ Pddg,
    const float* __restrict__ ws, float* __restrict__ out)
{
    __shared__ __align__(16) float sBcol[3][11][108];   // basis columns, t-pad 0
    __shared__ float s_i2x[196], s_i2y[225], sR2x[121], sR2y[121];
    __shared__ __align__(16) float rows[7][104];        // residual rows, t-pad 0
    __shared__ float dval[2][80];                       // half-dot partials
    __shared__ __align__(16) float cxs[12], cys[12];
    __shared__ float wlin[24];
    __shared__ float obsS[4][10];

    const int tid = threadIdx.x;
    const int e = blockIdx.x;

    // ---- cooperative staging ----
    for (int i = tid; i < 3*11*108; i += 256) {
        const int mat = i / 1188, rem = i - mat*1188;
        const int k = rem / 108, t = rem - k*108;
        const float* G = (mat == 0) ? Pg : (mat == 1 ? Pdg : Pddg);
        sBcol[mat][k][t] = (t < NUMPT) ? G[t*NVAR + k] : 0.0f;
    }
    for (int i = tid; i < 196; i += 256) s_i2x[i] = ws[WS_INV2X + i];
    for (int i = tid; i < 225; i += 256) s_i2y[i] = ws[WS_INV2Y + i];
    for (int i = tid; i < 121; i += 256) { sR2x[i] = ws[WS_R2X + i]; sR2y[i] = ws[WS_R2Y + i]; }
    if (tid >= 200 && tid < 240) {
        const int i = tid - 200;
        obsS[i/10][i%10] = inp[e*INPD + 5 + (i/10) + 5*(i%10)];
    }
    if (tid >= 64 && tid < 92) {        // zero 7 rows x 4 tail pads
        const int i = tid - 64;
        rows[i >> 2][100 + (i & 3)] = 0.0f;
    }
    if (tid == 92) cxs[11] = 0.0f;
    if (tid == 93) cys[11] = 0.0f;

    // ---- roles ----
    const bool isA = (tid < 200);
    const int tA = tid >> 1, hA = tid & 1;      // timepoint, half (obs + deriv)
    const bool isB = (tid < 154);
    const int hB = (tid >= 77) ? 1 : 0;
    const int dB = tid - 77*hB;
    const int rB = dB / 11, kB = dB - 11*rB;
    // rows: 0 SX(.P) 1 AX(.Pdd) 2 VX(.Pd) 3 SY(.P) 4 AY(.Pdd) 5 VY(.Pd) 6 LN(.P)
    const int mB = (rB==1||rB==4) ? 2 : ((rB==2||rB==5) ? 1 : 0);
    const float* colp = &sBcol[mB][kB][hB*52];
    const float* rowp = &rows[rB][hB*52];

    float bP[NVAR], bQ[NVAR];   // bQ = Pd row (even lane) or Pdd row (odd lane)
    if (isA) {
        const float* Qsrc = hA ? Pddg : Pdg;
        #pragma unroll
        for (int k = 0; k < NVAR; ++k) {
            bP[k] = Pg[tA*NVAR+k];
            bQ[k] = Qsrc[tA*NVAR+k];
        }
    }

    const float vx0 = ise[e*4 + 2], vy0 = ise[e*4 + 3];
    const float yub = yub_p[e], ylb = ylb_p[e];
    __syncthreads();

    // obstacle positions at own timepoint -> registers (5 per lane)
    const float DT = T_FIN_C / 99.0f;
    float xo[5], yo[5];
    if (isA) {
        const int ob0 = 5*hA;
        #pragma unroll
        for (int o = 0; o < 5; ++o) {
            xo[o] = fmaf(obsS[2][ob0+o], tA*DT, obsS[0][ob0+o]);
            yo[o] = fmaf(obsS[3][ob0+o], tA*DT, obsS[1][ob0+o]);
        }
    }

    // ---- lincost broadcast + c_bar init ----
    if (tid < 11) {
        float s = 0;
        #pragma unroll
        for (int c = 0; c < 4; ++c)
            s = fmaf(nn_out[e*8 + c], ws[WS_SVD + c*11 + tid], s);
        wlin[tid] = RHO_V_C * K_P_V_C * s;
    } else if (tid < 22) {
        const int k = tid - 11;
        float s = 0;
        #pragma unroll
        for (int c = 0; c < 4; ++c)
            s = fmaf(nn_out[e*8 + 4 + c], ws[WS_SPD + c*11 + k], s);
        wlin[tid] = RHO_OFFSET_C * K_P_C * s;
    }
    __syncthreads();

    float lam = 0.0f, cb = 0.0f;
    if (tid < 11) {
        const int k = tid;
        float a = vx0 * ws[WS_INV1X + k*14 + 12];
        #pragma unroll
        for (int j = 0; j < NVAR; ++j)
            a = fmaf(-wlin[j], ws[WS_INV1X + k*14 + j], a);
        cb = a; cxs[k] = a;
    } else if (tid < 22) {
        const int k = tid - 11;
        float a = vy0 * ws[WS_INV1Y + k*15 + 12];
        #pragma unroll
        for (int j = 0; j < NVAR; ++j)
            a = fmaf(-wlin[11 + j], ws[WS_INV1Y + k*15 + j], a);
        cb = a; cys[k] = a;
    }
    __syncthreads();

    // ---- main loop ----
    for (int it = 0; it < MAXIT; ++it) {
        // -------- phase A --------
        if (isA) {
            const float4 x0 = *(const float4*)&cxs[0];
            const float4 x1 = *(const float4*)&cxs[4];
            const float4 x2 = *(const float4*)&cxs[8];
            const float4 y0 = *(const float4*)&cys[0];
            const float4 y1 = *(const float4*)&cys[4];
            const float4 y2 = *(const float4*)&cys[8];
            const float px = DOT11(bP, x0, x1, x2);
            const float py = DOT11(bP, y0, y1, y2);
            const float qx = DOT11(bQ, x0, x1, x2);  // pxd (even) / pxdd (odd)
            const float qy = DOT11(bQ, y0, y1, y2);

            // obstacles (5 per lane), collapsed repulsion form:
            // d_o = max(1, sqrt(r2))/(A*B) exactly -> residual = (wc,ws)*f
            float srx = 0.0f, sry = 0.0f;
            #pragma unroll
            for (int o = 0; o < 5; ++o) {
                const float wc = px - xo[o], wsv = py - yo[o];
                const float aw = A_OBS_C * wsv, bw = B_OBS_C * wc;
                const float r2 = aw*aw + bw*bw;
                if (r2 > 0.0f) {
                    const float f = (r2 < ABSQ_C) ? (1.0f - AB_C * rsqrtf(r2)) : 0.0f;
                    srx = fmaf(wc, f, srx);
                    sry = fmaf(wsv, f, sry);
                } else {
                    srx -= A_OBS_C;
                }
            }
            const float mrx = srx + __shfl_xor(srx, 1);
            const float mry = sry + __shfl_xor(sry, 1);

            if (hA == 0) {
                rows[0][tA] = mrx;
                rows[3][tA] = mry;
                // velocity residual = p*(1 - dv/rv)
                const float rv2 = qx*qx + qy*qy;
                float vxr, vyr;
                if (rv2 > 0.0f) {
                    const float ri = rsqrtf(rv2);
                    const float dv = fminf(fmaxf(rv2*ri, V_MIN_C), V_MAX_C);
                    const float f = 1.0f - dv*ri;
                    vxr = qx*f; vyr = qy*f;
                } else { vxr = -V_MIN_C; vyr = 0.0f; }
                rows[2][tA] = vxr;  rows[5][tA] = vyr;
                // lane residual
                rows[6][tA] = fmaxf(0.0f, py - yub) - fmaxf(0.0f, ylb - py);
            } else {
                // acceleration residual (active only when |a| > A_MAX)
                const float ra2 = qx*qx + qy*qy;
                float axr = 0.0f, ayr = 0.0f;
                if (ra2 > A_MAX_C*A_MAX_C) {
                    const float ri = rsqrtf(ra2);
                    const float f = 1.0f - A_MAX_C*ri;
                    axr = qx*f; ayr = qy*f;
                }
                rows[1][tA] = axr;  rows[4][tA] = ayr;
            }
        }
        __syncthreads();

        // -------- phase B: 154 half-dots, 2-acc ILP --------
        if (isB) {
            float s0 = 0.0f, s1 = 0.0f;
            #pragma unroll
            for (int i = 0; i < 13; ++i) {
                const float4 rr = *(const float4*)&rowp[i*4];
                const float4 cc = *(const float4*)&colp[i*4];
                s0 = fmaf(rr.x, cc.x, s0); s1 = fmaf(rr.y, cc.y, s1);
                s0 = fmaf(rr.z, cc.z, s0); s1 = fmaf(rr.w, cc.w, s1);
            }
            dval[hB][dB] = s0 + s1;
        }
        __syncthreads();

        // -------- phase C (wave 0, lanes 0..21) --------
        if (tid < 22) {
            const int k = (tid < 11) ? tid : tid - 11;
            float u;
            if (tid < 11)   // rows 0..2: SX,AX,VX
                u = RHO_OBS_C * ((dval[0][k]      + dval[1][k])
                               + (dval[0][11 + k] + dval[1][11 + k])
                               + (dval[0][22 + k] + dval[1][22 + k]));
            else            // rows 3..6: SY,AY,VY,LN
                u = RHO_OBS_C * ((dval[0][33 + k] + dval[1][33 + k])
                               + (dval[0][44 + k] + dval[1][44 + k])
                               + (dval[0][55 + k] + dval[1][55 + k])
                               + (dval[0][66 + k] + dval[1][66 + k]));
            wlin[tid] = 2.0f*u - lam - cb;
            lam -= u;
        }
        __builtin_amdgcn_wave_barrier();
        if (tid < 22) {
            const int k = (tid < 11) ? tid : tid - 11;
            if (tid < 11) {
                float a = vx0 * s_i2x[k*14 + 12];
                #pragma unroll
                for (int j = 0; j < NVAR; ++j) {
                    a = fmaf(-wlin[j], s_i2x[k*14 + j], a);
                    a = fmaf(sR2x[k*11 + j], cxs[j], a);
                }
                cxs[k] = a;
            } else {
                float a = vy0 * s_i2y[k*15 + 12];
                #pragma unroll
                for (int j = 0; j < NVAR; ++j) {
                    a = fmaf(-wlin[11 + j], s_i2y[k*15 + j], a);
                    a = fmaf(sR2y[k*11 + j], cys[j], a);
                }
                cys[k] = a;
            }
        }
        __syncthreads();
    }

    if (tid < NVAR) {
        out[e*22 + tid]      = cxs[tid];
        out[e*22 + 11 + tid] = cys[tid];
    }
}

// ---------------------------------------------------------------------------
extern "C" void kernel_launch(void* const* d_in, const int* in_sizes, int n_in,
                              void* d_out, int out_size, void* d_ws, size_t ws_size,
                              hipStream_t stream)
{
    (void)in_sizes; (void)n_in; (void)out_size; (void)ws_size;
    const float* inp    = (const float*)d_in[0];
    const float* ise    = (const float*)d_in[1];
    const float* traj   = (const float*)d_in[2];
    const float* yub    = (const float*)d_in[3];
    const float* ylb    = (const float*)d_in[4];
    const float* eps    = (const float*)d_in[5];
    const float* enc_w1 = (const float*)d_in[6];
    const float* enc_b1 = (const float*)d_in[7];
    const float* enc_w2 = (const float*)d_in[8];
    const float* enc_b2 = (const float*)d_in[9];
    const float* wmu    = (const float*)d_in[10];
    const float* bmu    = (const float*)d_in[11];
    const float* wlv    = (const float*)d_in[12];
    const float* blv    = (const float*)d_in[13];
    const float* dec_w1 = (const float*)d_in[14];
    const float* dec_b1 = (const float*)d_in[15];
    const float* dec_w2 = (const float*)d_in[16];
    const float* dec_b2 = (const float*)d_in[17];
    const float* dec_w3 = (const float*)d_in[18];
    const float* dec_b3 = (const float*)d_in[19];
    const float* P      = (const float*)d_in[20];
    const float* Pd     = (const float*)d_in[21];
    const float* Pdd    = (const float*)d_in[22];
    const float* mean   = (const float*)d_in[23];
    const float* stdv   = (const float*)d_in[24];

    float* ws   = (float*)d_ws;
    float* nn   = ws + WS_BIG;                        // 1024 x 8 fp32
    __bf16* bfb = (__bf16*)(ws + WS_BIG + BATCH*8);
    __bf16* enc_in = bfb;                             // 1024 x 256
    __bf16* dec_in = enc_in + (size_t)BATCH*256;      // 1024 x 64
    __bf16* hA     = dec_in + (size_t)BATCH*64;       // 1024 x 1024
    __bf16* hB     = hA + (size_t)BATCH*HID;          // 1024 x 1024
    __bf16* wt1    = hB + (size_t)BATCH*HID;          // 1024 x 256
    __bf16* wt2    = wt1 + (size_t)HID*256;           // 1024 x 1024
    __bf16* wt3    = wt2 + (size_t)HID*HID;           // 1024 x 64
    __bf16* wt4    = wt3 + (size_t)HID*64;            // 1024 x 1024
    float* outf = (float*)d_out;

    setup_kernel<<<4 + 1024 + 9472, 256, 0, stream>>>(
        P, Pd, Pdd, ws, inp, traj, mean, stdv, enc_in, dec_in,
        enc_w1, enc_w2, dec_w1, dec_w2, wt1, wt2, wt3, wt4);

    dim3 g(16, 32);   // 32-row tiles -> 512 blocks -> 2 blocks/CU
    gemm_mfma<<<g, 256, 0, stream>>>(enc_in, wt1, enc_b1, hA, 256);
    gemm_mfma<<<g, 256, 0, stream>>>(hA, wt2, enc_b2, hB, 1024);
    z_kernel<<<BATCH, 64, 0, stream>>>(hB, wmu, bmu, wlv, blv, eps, dec_in);
    gemm_mfma<<<g, 256, 0, stream>>>(dec_in, wt3, dec_b1, hA, 64);
    gemm_mfma<<<g, 256, 0, stream>>>(hA, wt4, dec_b2, hB, 1024);
    out8_kernel<<<BATCH, 64, 0, stream>>>(hB, dec_w3, dec_b3, nn);

    solver_kernel<<<BATCH, 256, 0, stream>>>(nn, inp, ise, yub, ylb,
                                             P, Pd, Pdd, ws, outf);
}